// Round 4
// baseline (1181.270 us; speedup 1.0000x reference)
//
#include <hip/hip_runtime.h>
#include <hip/hip_fp16.h>

#define B_SZ 4
#define T_SEQ 2048
#define NH 16
#define HD 64
#define DMODEL 1024
#define MTOT (B_SZ * T_SEQ)   // 8192

typedef __bf16 bf16x8 __attribute__((ext_vector_type(8)));
typedef float f32x4 __attribute__((ext_vector_type(4)));
typedef float f32x2 __attribute__((ext_vector_type(2)));
typedef _Float16 f16x4 __attribute__((ext_vector_type(4)));

__device__ __forceinline__ unsigned short f2bf(float f) {
    union { float f; unsigned int i; } c; c.f = f;
    unsigned int u = c.i;
    u += 0x7fffu + ((u >> 16) & 1u);   // round-to-nearest-even
    return (unsigned short)(u >> 16);
}
__device__ __forceinline__ float sigm(float x) { return 1.f / (1.f + __expf(-x)); }

// async global->LDS DMA, 16B/lane (GEMM staging only)
__device__ __forceinline__ void dma16(const void* g, void* l) {
    __builtin_amdgcn_global_load_lds(
        (const __attribute__((address_space(1))) void*)g,
        (__attribute__((address_space(3))) void*)l, 16, 0, 0);
}

// DPP row_ror butterfly via builtin (compiler inserts hazard nops).
template <int CTRL>
__device__ __forceinline__ float dppadd(float x) {
    int v = __builtin_amdgcn_update_dpp(0, __builtin_bit_cast(int, x), CTRL, 0xf, 0xf, false);
    return x + __builtin_bit_cast(float, v);
}
__device__ __forceinline__ float rowsum16(float x) {
    x = dppadd<0x128>(x);
    x = dppadd<0x124>(x);
    x = dppadd<0x122>(x);
    x = dppadd<0x121>(x);
    return x;
}

// Three independent 16-lane row reductions (compiler interleaves chains).
__device__ __forceinline__ void rowsum3(float& a, float& b, float& c) {
    a = rowsum16(a);
    b = rowsum16(b);
    c = rowsum16(c);
}

// Three independent 32-lane reductions: lane^16 exchange first (the three
// swizzles pipeline in the LDS pipe, hiding latency), then the proven
// 4-stage DPP row reduction. Lanes 0-31 / 32-63 are independent columns;
// shfl_xor(16) stays within each 32-lane half, so no cross-column mixing.
__device__ __forceinline__ void rowsum32_3(float& a, float& b, float& c) {
    a += __shfl_xor(a, 16);
    b += __shfl_xor(b, 16);
    c += __shfl_xor(c, 16);
    a = rowsum16(a);
    b = rowsum16(b);
    c = rowsum16(c);
}

// ---------------------------------------------------------------- LayerNorm
__global__ __launch_bounds__(256, 1) void k_ln(const float* __restrict__ x,
                                               const float* __restrict__ lnw,
                                               const float* __restrict__ lnb,
                                               unsigned short* __restrict__ xn) {
    const int m = blockIdx.x;
    const int t = threadIdx.x;
    float4 xv = ((const float4*)(x + (size_t)m * DMODEL))[t];
    float s = xv.x + xv.y + xv.z + xv.w;
    float s2 = xv.x * xv.x + xv.y * xv.y + xv.z * xv.z + xv.w * xv.w;
#pragma unroll
    for (int off = 32; off >= 1; off >>= 1) {
        s += __shfl_xor(s, off);
        s2 += __shfl_xor(s2, off);
    }
    __shared__ float red[8];
    const int wid = t >> 6;
    if ((t & 63) == 0) { red[wid] = s; red[4 + wid] = s2; }
    __syncthreads();
    if (t == 0) {
        float su = red[0] + red[1] + red[2] + red[3];
        float sq = red[4] + red[5] + red[6] + red[7];
        float mu = su * (1.f / DMODEL);
        float var = sq * (1.f / DMODEL) - mu * mu;
        red[0] = mu;
        red[1] = rsqrtf(var + 1e-5f);
    }
    __syncthreads();
    float mu = red[0], rstd = red[1];
    float4 w4 = ((const float4*)lnw)[t];
    float4 b4 = ((const float4*)lnb)[t];
    ushort4 o;
    o.x = f2bf((xv.x - mu) * rstd * w4.x + b4.x);
    o.y = f2bf((xv.y - mu) * rstd * w4.y + b4.y);
    o.z = f2bf((xv.z - mu) * rstd * w4.z + b4.z);
    o.w = f2bf((xv.w - mu) * rstd * w4.w + b4.w);
    ((ushort4*)(xn + (size_t)m * DMODEL))[t] = o;
}

// ------------------------------------------- fp32 -> bf16 weight conversion
struct WPtrs { const float* p0; const float* p1; const float* p2; const float* p3; const float* p4; };

__global__ __launch_bounds__(256, 1) void k_wconv(WPtrs w, unsigned short* __restrict__ dst) {
    const int plane = blockIdx.y;
    const float* src = plane == 0 ? w.p0 : plane == 1 ? w.p1 : plane == 2 ? w.p2
                                                             : plane == 3 ? w.p3 : w.p4;
    const size_t i = ((size_t)blockIdx.x * 256 + threadIdx.x) * 8;
    float4 f0 = *(const float4*)(src + i);
    float4 f1 = *(const float4*)(src + i + 4);
    uint4 o;
    o.x = (unsigned)f2bf(f0.x) | ((unsigned)f2bf(f0.y) << 16);
    o.y = (unsigned)f2bf(f0.z) | ((unsigned)f2bf(f0.w) << 16);
    o.z = (unsigned)f2bf(f1.x) | ((unsigned)f2bf(f1.y) << 16);
    o.w = (unsigned)f2bf(f1.z) | ((unsigned)f2bf(f1.w) << 16);
    *(uint4*)(dst + (size_t)plane * 1048576 + i) = o;
}

__global__ __launch_bounds__(256, 1) void k_cvt1(const float* __restrict__ src,
                                                 unsigned short* __restrict__ dst) {
    const size_t i = ((size_t)blockIdx.x * 256 + threadIdx.x) * 8;
    float4 f0 = *(const float4*)(src + i);
    float4 f1 = *(const float4*)(src + i + 4);
    uint4 o;
    o.x = (unsigned)f2bf(f0.x) | ((unsigned)f2bf(f0.y) << 16);
    o.y = (unsigned)f2bf(f0.z) | ((unsigned)f2bf(f0.w) << 16);
    o.z = (unsigned)f2bf(f1.x) | ((unsigned)f2bf(f1.y) << 16);
    o.w = (unsigned)f2bf(f1.z) | ((unsigned)f2bf(f1.w) << 16);
    *(uint4*)(dst + i) = o;
}

// ------------------------------------------------- 128x128 bf16 MFMA tile GEMM
template <int KDIM>
__device__ __forceinline__ void gemm128(const unsigned short* __restrict__ A,
                                        const unsigned short* __restrict__ Bw,
                                        int m0, int n0, f32x4 acc[4][4]) {
    __shared__ __align__(16) unsigned short sA[128 * 32];
    __shared__ __align__(16) unsigned short sB[128 * 32];

    const int t = threadIdx.x;
    const int lane = t & 63;
    const int wv = t >> 6;
    const int wm = wv >> 1, wn = wv & 1;
    const int ml = lane & 15, kq = lane >> 4;

#pragma unroll
    for (int i = 0; i < 4; i++)
#pragma unroll
        for (int j = 0; j < 4; j++) {
            f32x4 z; z[0] = 0.f; z[1] = 0.f; z[2] = 0.f; z[3] = 0.f;
            acc[i][j] = z;
        }

    const unsigned short* pA = A + (size_t)m0 * KDIM;
    const unsigned short* pB = Bw + (size_t)n0 * KDIM;
    const unsigned short* gA0 = pA + (size_t)(t >> 2) * KDIM + (t & 3) * 8;
    const unsigned short* gA1 = gA0 + (size_t)64 * KDIM;
    const unsigned short* gB0 = pB + (size_t)(t >> 2) * KDIM + (t & 3) * 8;
    const unsigned short* gB1 = gB0 + (size_t)64 * KDIM;
    unsigned short* lA0 = sA + wv * 512;
    unsigned short* lA1 = lA0 + 2048;
    unsigned short* lB0 = sB + wv * 512;
    unsigned short* lB1 = lB0 + 2048;

    for (int kb = 0; kb < KDIM / 32; kb++) {
        const int ko = kb * 32;
        dma16(gA0 + ko, lA0);
        dma16(gA1 + ko, lA1);
        dma16(gB0 + ko, lB0);
        dma16(gB1 + ko, lB1);
        __syncthreads();
        bf16x8 af[4], bfr[4];
#pragma unroll
        for (int mt = 0; mt < 4; mt++)
            af[mt] = *(const bf16x8*)&sA[(wm * 64 + mt * 16 + ml) * 32 + kq * 8];
#pragma unroll
        for (int nt = 0; nt < 4; nt++)
            bfr[nt] = *(const bf16x8*)&sB[(wn * 64 + nt * 16 + ml) * 32 + kq * 8];
#pragma unroll
        for (int mt = 0; mt < 4; mt++)
#pragma unroll
            for (int nt = 0; nt < 4; nt++)
                acc[mt][nt] = __builtin_amdgcn_mfma_f32_16x16x32_bf16(af[mt], bfr[nt], acc[mt][nt], 0, 0, 0);
        __syncthreads();
    }
}

// -------------------------------------------- fused 5-way projection GEMM
// OT = float (fp32 stream path) or _Float16 (fallback)
template <typename OT>
__global__ __launch_bounds__(256, 1) void k_proj(const unsigned short* __restrict__ xn,
                                                 const unsigned short* __restrict__ wbf,
                                                 const float* __restrict__ ba,
                                                 const float* __restrict__ baR,
                                                 OT* __restrict__ qo, OT* __restrict__ ko,
                                                 OT* __restrict__ vo, OT* __restrict__ ao,
                                                 OT* __restrict__ aRo) {
    const int m0 = blockIdx.x * 128;
    const int yt = blockIdx.y;
    const int widx = yt >> 3;
    const int n0 = (yt & 7) * 128;
    const unsigned short* W = wbf + (size_t)widx * 1048576;
    f32x4 acc[4][4];
    gemm128<1024>(xn, W, m0, n0, acc);

    OT* outp = widx == 0 ? qo : widx == 1 ? ko : widx == 2 ? vo : widx == 3 ? ao : aRo;
    const float* bias = (widx == 3) ? ba : (widx == 4) ? baR : (const float*)0;
    const int lane = threadIdx.x & 63;
    const int wv = threadIdx.x >> 6;
    const int wm = wv >> 1, wn = wv & 1;
    const int ml = lane & 15, kq = lane >> 4;
#pragma unroll
    for (int mt = 0; mt < 4; mt++)
#pragma unroll
        for (int nt = 0; nt < 4; nt++) {
            const int rowg = m0 + wm * 64 + mt * 16 + kq * 4;
            const int colg = n0 + wn * 64 + nt * 16 + ml;
            float bval = bias ? bias[colg] : 0.f;
#pragma unroll
            for (int r = 0; r < 4; r++) {
                float v = acc[mt][nt][r];
                if (widx >= 3) v = sigm(v + bval);
                outp[(size_t)(rowg + r) * DMODEL + colg] = (OT)v;
            }
        }
}

// --------------------------------------------------- beta/gamma skinny GEMM
__global__ __launch_bounds__(256, 1) void k_bg(const unsigned short* __restrict__ xn,
                                               const float* __restrict__ Wb,
                                               const float* __restrict__ bb,
                                               const float* __restrict__ Wg,
                                               const float* __restrict__ bgp,
                                               f32x2* __restrict__ bgpk) {
    const int m = blockIdx.x;
    const int t = threadIdx.x;
    const int h = t >> 4, seg = t & 15;
    const ushort4* xr = (const ushort4*)(xn + (size_t)m * DMODEL + seg * 64);
    const float4* wbr = (const float4*)(Wb + (size_t)h * DMODEL + seg * 64);
    const float4* wgr = (const float4*)(Wg + (size_t)h * DMODEL + seg * 64);
    float db = 0.f, dg = 0.f;
#pragma unroll
    for (int u = 0; u < 16; u++) {
        ushort4 a = xr[u];
        float4 w1 = wbr[u], w2 = wgr[u];
        union { unsigned int i; float f; } c0, c1, c2, c3;
        c0.i = ((unsigned int)a.x) << 16; c1.i = ((unsigned int)a.y) << 16;
        c2.i = ((unsigned int)a.z) << 16; c3.i = ((unsigned int)a.w) << 16;
        db += c0.f * w1.x + c1.f * w1.y + c2.f * w1.z + c3.f * w1.w;
        dg += c0.f * w2.x + c1.f * w2.y + c2.f * w2.z + c3.f * w2.w;
    }
#pragma unroll
    for (int off = 1; off < 16; off <<= 1) {
        db += __shfl_xor(db, off);
        dg += __shfl_xor(dg, off);
    }
    if (seg == 0) {
        f32x2 o;
        o[0] = sigm(db + bb[h]);
        o[1] = sigm(dg + bgp[h]);
        bgpk[(size_t)m * NH + h] = o;
    }
}

// ------------------------------------------- k normalization (in-place)
__global__ __launch_bounds__(256, 1) void k_prep16(__half* __restrict__ kb) {
    const int row = blockIdx.x * 16 + (threadIdx.x >> 4);
    const int tr = threadIdx.x & 15;
    const int bh = row >> 11, t = row & 2047;
    const size_t idx = ((size_t)((bh >> 4) * T_SEQ + t)) * DMODEL + (bh & 15) * 64 + tr * 4;
    f16x4 k4 = *(const f16x4*)((const __half*)kb + idx);
    float k0 = (float)k4[0], k1 = (float)k4[1], k2 = (float)k4[2], k3 = (float)k4[3];
    float ss = k0 * k0 + k1 * k1 + k2 * k2 + k3 * k3;
    ss = rowsum16(ss);
    float inv = 1.f / fmaxf(sqrtf(ss), 1e-12f);
    f16x4 o;
    o[0] = (_Float16)(k0 * inv); o[1] = (_Float16)(k1 * inv);
    o[2] = (_Float16)(k2 * inv); o[3] = (_Float16)(k3 * inv);
    *(f16x4*)(kb + idx) = o;
}

__global__ __launch_bounds__(256, 1) void k_prep32(float* __restrict__ kb) {
    const int row = blockIdx.x * 16 + (threadIdx.x >> 4);
    const int tr = threadIdx.x & 15;
    const int bh = row >> 11, t = row & 2047;
    const size_t idx = ((size_t)((bh >> 4) * T_SEQ + t)) * DMODEL + (bh & 15) * 64 + tr * 4;
    f32x4 k4 = *(const f32x4*)(kb + idx);
    float ss = k4[0] * k4[0] + k4[1] * k4[1] + k4[2] * k4[2] + k4[3] * k4[3];
    ss = rowsum16(ss);
    float inv = 1.f / fmaxf(sqrtf(ss), 1e-12f);
    f32x4 o;
    o[0] = k4[0] * inv; o[1] = k4[1] * inv; o[2] = k4[2] * inv; o[3] = k4[3] * inv;
    *(f32x4*)(kb + idx) = o;
}

// ------------------------------------------------------------- the scan, fp32
// 512 blocks (2 blocks/CU -> 2 waves/SIMD, doubles occupancy to fill the
// ~46% stall cycles measured at 1 wave/SIMD). Each thread owns 2 j-elements
// (packed f32x2); 32 lanes per column; reduction = shfl_xor(16) + 4-stage DPP.
// XCD co-location preserved: same-bh blocks at blk = bh + 64k, 64 % 8 == 0.
// NOTE: T_SEQ % 6 != 0 -> all o-stores guarded by s < T_SEQ (last iteration
// computes steps 2046..2051; unguarded stores would corrupt batch b+1 rows).
__global__ __launch_bounds__(256, 2) void k_scan32(const float* __restrict__ qb,
                                                   const float* __restrict__ knb,
                                                   const float* __restrict__ vb,
                                                   const float* __restrict__ ab,
                                                   const float* __restrict__ aRb,
                                                   const f32x2* __restrict__ bgpk,
                                                   unsigned short* __restrict__ ob) {
    const int blk = blockIdx.x;
    const int bh = blk & 63, cg = blk >> 6;   // cg in [0,8)
    const int b = bh >> 4, h = bh & 15;
    const int t = threadIdx.x;
    const int col = t >> 5, lr = t & 31;      // 8 cols/block, 32 lanes/col
    const int ii = cg * 8 + col;
    const int j0 = lr * 2;

    const size_t blkoff = (size_t)b * T_SEQ * DMODEL + h * 64;  // block-uniform
    const float* pq = qb + blkoff;
    const float* pk = knb + blkoff;
    const float* pa = ab + blkoff;
    const float* pr = aRb + blkoff;
    const float* pvb = vb + blkoff;
    const f32x2* pbg = bgpk + (size_t)b * T_SEQ * NH + h;
    unsigned short* obp = ob + blkoff + ii;

    f32x2 S2 = {0.f, 0.f}, R2 = {0.f, 0.f};

    f32x2 rk[6], rq[6], ra[6], rr[6];
    float rv[6];
    f32x2 rbg[6];

#pragma unroll
    for (int p = 0; p < 6; p++) {
        const size_t vo = (size_t)p * DMODEL;
        rk[p] = *(const f32x2*)(pk + vo + j0);
        rq[p] = *(const f32x2*)(pq + vo + j0);
        ra[p] = *(const f32x2*)(pa + vo + j0);
        rr[p] = *(const f32x2*)(pr + vo + j0);
        rv[p] = pvb[vo + ii];
        rbg[p] = pbg[(size_t)p * NH];
    }

    float oA, oB, oC;

#define SCAN_BODY32(P, ODEST)                                                       \
    {                                                                               \
        const f32x2 kn2 = rk[P], a2 = ra[P], x2 = rr[P], q2 = rq[P];                \
        const float vc = rv[P];                                                     \
        const float beta = rbg[P][0], gamma = rbg[P][1];                            \
        const f32x2 Sd = a2 * S2;                                                   \
        const f32x2 Rd = x2 * R2;                                                   \
        const f32x2 pp = S2 * kn2;                                                  \
        const f32x2 kq2 = Sd * kn2;                                                 \
        const f32x2 kR2 = Rd * kn2;                                                 \
        float pred = pp[0] + pp[1];                                                 \
        float kp = kq2[0] + kq2[1];                                                 \
        float kpR = kR2[0] + kR2[1];                                                \
        rowsum32_3(pred, kp, kpR);                                                  \
        const float rres = fminf(fmaxf(vc - pred, -1.f), 1.f);                      \
        const float cS = beta * (vc - kp);                                          \
        const float cR = gamma * (rres - kpR);                                      \
        const f32x2 cS2 = {cS, cS}, cR2 = {cR, cR};                                 \
        S2 = cS2 * kn2 + Sd;                                                        \
        R2 = cR2 * kn2 + Rd;                                                        \
        const f32x2 ov = (S2 + R2) * q2;                                            \
        ODEST = ov[0] + ov[1];                                                      \
        /* prefetch step st+P+6 into slot P (old slot value fully consumed) */      \
        {                                                                           \
            const int sp = (st + (P) + 6) & (T_SEQ - 1);                            \
            const size_t vo = (size_t)sp * DMODEL;                                  \
            rk[P] = *(const f32x2*)(pk + vo + j0);                                  \
            rq[P] = *(const f32x2*)(pq + vo + j0);                                  \
            ra[P] = *(const f32x2*)(pa + vo + j0);                                  \
            rr[P] = *(const f32x2*)(pr + vo + j0);                                  \
            rv[P] = pvb[vo + ii];                                                   \
            rbg[P] = pbg[(size_t)sp * NH];                                          \
        }                                                                           \
    }

#define FLUSH3(SBASE)                                                               \
    {                                                                               \
        rowsum32_3(oA, oB, oC);                                                     \
        if (lr == 0) {                                                              \
            if ((SBASE) < T_SEQ)     obp[(size_t)(SBASE) * DMODEL] = f2bf(oA);      \
            if ((SBASE) + 1 < T_SEQ) obp[(size_t)((SBASE) + 1) * DMODEL] = f2bf(oB);\
            if ((SBASE) + 2 < T_SEQ) obp[(size_t)((SBASE) + 2) * DMODEL] = f2bf(oC);\
        }                                                                           \
    }

    for (int st = 0; st < T_SEQ; st += 6) {
        SCAN_BODY32(0, oA)
        SCAN_BODY32(1, oB)
        SCAN_BODY32(2, oC)
        FLUSH3(st)
        SCAN_BODY32(3, oA)
        SCAN_BODY32(4, oB)
        SCAN_BODY32(5, oC)
        FLUSH3(st + 3)
    }
#undef SCAN_BODY32
#undef FLUSH3
}

// ------------------------------------------------------------- the scan, fp16
// Fallback path (proven 944us kernel) used if ws_size is too small for fp32
// stream planes.
__global__ __launch_bounds__(256, 1) void k_scan16(const __half* __restrict__ qb,
                                                   const __half* __restrict__ knb,
                                                   const __half* __restrict__ vb,
                                                   const __half* __restrict__ ab,
                                                   const __half* __restrict__ aRb,
                                                   const f32x2* __restrict__ bgpk,
                                                   unsigned short* __restrict__ ob) {
    const int blk = blockIdx.x;
    const int bh = blk & 63, cg = blk >> 6;
    const int b = bh >> 4, h = bh & 15;
    const int t = threadIdx.x;
    const int col = t >> 4, tr = t & 15;
    const int ii = cg * 16 + col;
    const int j0 = tr * 4;

    const size_t vecbase = ((size_t)b * T_SEQ) * DMODEL + h * 64 + j0;
    const size_t vbase = ((size_t)b * T_SEQ) * DMODEL + h * 64 + ii;
    const size_t bgbase = ((size_t)b * T_SEQ) * NH + h;

    const __half* pk = knb + vecbase;
    const __half* pq = qb + vecbase;
    const __half* pa = ab + vecbase;
    const __half* pr = aRb + vecbase;

    float S0 = 0, S1 = 0, S2 = 0, S3 = 0, R0 = 0, R1 = 0, R2 = 0, R3 = 0;

    f16x4 rk[6], rq[6], ra[6], rr[6];
    __half rv[6];
    f32x2 rbg[6];
    f32x4 fkn[6], fq[6], fa[6], fr[6];
    float fv[6];

#pragma unroll
    for (int p = 0; p < 6; p++) {
        const size_t voff = (size_t)p * DMODEL;
        rk[p] = *(const f16x4*)(pk + voff);
        rq[p] = *(const f16x4*)(pq + voff);
        ra[p] = *(const f16x4*)(pa + voff);
        rr[p] = *(const f16x4*)(pr + voff);
        rv[p] = vb[vbase + voff];
        rbg[p] = bgpk[bgbase + (size_t)p * NH];
    }
    fkn[0][0] = (float)rk[0][0]; fkn[0][1] = (float)rk[0][1]; fkn[0][2] = (float)rk[0][2]; fkn[0][3] = (float)rk[0][3];
    fq[0][0] = (float)rq[0][0]; fq[0][1] = (float)rq[0][1]; fq[0][2] = (float)rq[0][2]; fq[0][3] = (float)rq[0][3];
    fa[0][0] = (float)ra[0][0]; fa[0][1] = (float)ra[0][1]; fa[0][2] = (float)ra[0][2]; fa[0][3] = (float)ra[0][3];
    fr[0][0] = (float)rr[0][0]; fr[0][1] = (float)rr[0][1]; fr[0][2] = (float)rr[0][2]; fr[0][3] = (float)rr[0][3];
    fv[0] = (float)rv[0];

#define SCAN_BODY(P, PN)                                                              \
    {                                                                                 \
        const int s = st + (P);                                                       \
        const float beta = rbg[P][0], gamma = rbg[P][1];                              \
        {                                                                             \
            const size_t voff = (size_t)((s + 6) & (T_SEQ - 1)) * DMODEL;             \
            rk[P] = *(const f16x4*)(pk + voff);                                       \
            rq[P] = *(const f16x4*)(pq + voff);                                       \
            ra[P] = *(const f16x4*)(pa + voff);                                       \
            rr[P] = *(const f16x4*)(pr + voff);                                       \
            rv[P] = vb[vbase + voff];                                                 \
        }                                                                             \
        fkn[PN][0] = (float)rk[PN][0]; fkn[PN][1] = (float)rk[PN][1];                 \
        fkn[PN][2] = (float)rk[PN][2]; fkn[PN][3] = (float)rk[PN][3];                 \
        fq[PN][0] = (float)rq[PN][0]; fq[PN][1] = (float)rq[PN][1];                   \
        fq[PN][2] = (float)rq[PN][2]; fq[PN][3] = (float)rq[PN][3];                   \
        fa[PN][0] = (float)ra[PN][0]; fa[PN][1] = (float)ra[PN][1];                   \
        fa[PN][2] = (float)ra[PN][2]; fa[PN][3] = (float)ra[PN][3];                   \
        fr[PN][0] = (float)rr[PN][0]; fr[PN][1] = (float)rr[PN][1];                   \
        fr[PN][2] = (float)rr[PN][2]; fr[PN][3] = (float)rr[PN][3];                   \
        fv[PN] = (float)rv[PN];                                                       \
        {                                                                             \
            const float kn0 = fkn[P][0], kn1 = fkn[P][1], kn2 = fkn[P][2], kn3 = fkn[P][3]; \
            const float a0 = fa[P][0], a1 = fa[P][1], a2 = fa[P][2], a3 = fa[P][3];   \
            const float x0 = fr[P][0], x1 = fr[P][1], x2 = fr[P][2], x3 = fr[P][3];   \
            const float vc = fv[P];                                                   \
            float pred = S0 * kn0 + S1 * kn1 + S2 * kn2 + S3 * kn3;                   \
            float Sd0 = a0 * S0, Sd1 = a1 * S1, Sd2 = a2 * S2, Sd3 = a3 * S3;         \
            float Rd0 = x0 * R0, Rd1 = x1 * R1, Rd2 = x2 * R2, Rd3 = x3 * R3;         \
            float kp = Sd0 * kn0 + Sd1 * kn1 + Sd2 * kn2 + Sd3 * kn3;                 \
            float kpR = Rd0 * kn0 + Rd1 * kn1 + Rd2 * kn2 + Rd3 * kn3;                \
            pred = rowsum16(pred);                                                    \
            kp = rowsum16(kp);                                                        \
            kpR = rowsum16(kpR);                                                      \
            const float rres = fminf(fmaxf(vc - pred, -1.f), 1.f);                    \
            const float cS = beta * (vc - kp);                                        \
            const float cR = gamma * (rres - kpR);                                    \
            S0 = fmaf(cS, kn0, Sd0); S1 = fmaf(cS, kn1, Sd1);                         \
            S2 = fmaf(cS, kn2, Sd2); S3 = fmaf(cS, kn3, Sd3);                         \
            R0 = fmaf(cR, kn0, Rd0); R1 = fmaf(cR, kn1, Rd1);                         \
            R2 = fmaf(cR, kn2, Rd2); R3 = fmaf(cR, kn3, Rd3);                         \
            float o = (S0 + R0) * fq[P][0] + (S1 + R1) * fq[P][1] +                   \
                      (S2 + R2) * fq[P][2] + (S3 + R3) * fq[P][3];                    \
            o = rowsum16(o);                                                          \
            if (tr == 0 && s < T_SEQ)                                                 \
                ob[vbase + (size_t)s * DMODEL] = f2bf(o);                             \
        }                                                                             \
        rbg[P] = bgpk[bgbase + (size_t)((s + 6) & (T_SEQ - 1)) * NH];                 \
    }

    for (int st = 0; st < T_SEQ; st += 6) {
        SCAN_BODY(0, 1)
        SCAN_BODY(1, 2)
        SCAN_BODY(2, 3)
        SCAN_BODY(3, 4)
        SCAN_BODY(4, 5)
        SCAN_BODY(5, 0)
    }
#undef SCAN_BODY
}

// ---------------------------------------------------- output GEMM + residual
__global__ __launch_bounds__(256, 1) void k_out(const unsigned short* __restrict__ ob,
                                                const unsigned short* __restrict__ wobf,
                                                const float* __restrict__ x,
                                                float* __restrict__ out) {
    const int m0 = blockIdx.x * 128;
    const int n0 = blockIdx.y * 128;
    f32x4 acc[4][4];
    gemm128<1024>(ob, wobf, m0, n0, acc);
    const int lane = threadIdx.x & 63;
    const int wv = threadIdx.x >> 6;
    const int wm = wv >> 1, wn = wv & 1;
    const int ml = lane & 15, kq = lane >> 4;
#pragma unroll
    for (int mt = 0; mt < 4; mt++)
#pragma unroll
        for (int nt = 0; nt < 4; nt++) {
            const int rowg = m0 + wm * 64 + mt * 16 + kq * 4;
            const int colg = n0 + wn * 64 + nt * 16 + ml;
#pragma unroll
            for (int r = 0; r < 4; r++) {
                size_t idx = (size_t)(rowg + r) * DMODEL + colg;
                out[idx] = acc[mt][nt][r] + x[idx];
            }
        }
}

extern "C" void kernel_launch(void* const* d_in, const int* in_sizes, int n_in,
                              void* d_out, int out_size, void* d_ws, size_t ws_size,
                              hipStream_t stream) {
    const float* x = (const float*)d_in[0];
    const float* Wq = (const float*)d_in[1];
    const float* Wk = (const float*)d_in[2];
    const float* Wv = (const float*)d_in[3];
    const float* Wa = (const float*)d_in[4];
    const float* ba = (const float*)d_in[5];
    const float* Wb = (const float*)d_in[6];
    const float* bb = (const float*)d_in[7];
    const float* Wg = (const float*)d_in[8];
    const float* bg = (const float*)d_in[9];
    const float* WaR = (const float*)d_in[10];
    const float* baR = (const float*)d_in[11];
    const float* Wo = (const float*)d_in[12];
    const float* lnw = (const float*)d_in[13];
    const float* lnb = (const float*)d_in[14];

    const size_t SZH = 16777216ULL;   // fp16/bf16 plane bytes (8192*1024*2)
    const size_t SZF = 33554432ULL;   // fp32 plane bytes (8192*1024*4)
    const size_t need32 = 5 * SZF + SZH + 2097152ULL;   // ~178 MB
    const size_t need16 = 6 * SZH + 2097152ULL;         // ~98 MB

    char* ws = (char*)d_ws;
    // d_out doubles as scratch for bf16 projection weights (10 MB of 32 MB);
    // only read by k_proj, fully overwritten by k_out at the end.
    unsigned short* wbf = (unsigned short*)d_out;
    WPtrs wp{Wq, Wk, Wv, Wa, WaR};

    if (ws_size >= need32) {
        // ---------------- fp32 stream path ----------------
        float* qb = (float*)(ws + 0 * SZF);
        float* kb = (float*)(ws + 1 * SZF);
        float* vb = (float*)(ws + 2 * SZF);
        float* ab = (float*)(ws + 3 * SZF);
        float* aRb = (float*)(ws + 4 * SZF);
        unsigned short* xn = (unsigned short*)(ws + 5 * SZF);   // bf16; reused for o
        f32x2* bgpk = (f32x2*)(ws + 5 * SZF + SZH);
        unsigned short* wobf = (unsigned short*)qb;             // qb dead after scan

        k_wconv<<<dim3(512, 5), dim3(256), 0, stream>>>(wp, wbf);
        k_ln<<<dim3(MTOT), dim3(256), 0, stream>>>(x, lnw, lnb, xn);
        k_proj<float><<<dim3(64, 40), dim3(256), 0, stream>>>(xn, wbf, ba, baR, qb, kb, vb, ab, aRb);
        k_bg<<<dim3(MTOT), dim3(256), 0, stream>>>(xn, Wb, bb, Wg, bg, bgpk);
        k_prep32<<<dim3(MTOT * NH / 16), dim3(256), 0, stream>>>(kb);
        k_scan32<<<dim3(512), dim3(256), 0, stream>>>(qb, kb, vb, ab, aRb, bgpk, xn);
        k_cvt1<<<dim3(512), dim3(256), 0, stream>>>(Wo, wobf);
        k_out<<<dim3(64, 8), dim3(256), 0, stream>>>(xn, wobf, x, (float*)d_out);
    } else if (ws_size >= need16) {
        // ---------------- fp16 fallback (previous proven path) ----------------
        __half* qb = (__half*)(ws + 0 * SZH);
        __half* kb = (__half*)(ws + 1 * SZH);
        __half* vb = (__half*)(ws + 2 * SZH);
        __half* ab = (__half*)(ws + 3 * SZH);
        __half* aRb = (__half*)(ws + 4 * SZH);
        unsigned short* xn = (unsigned short*)(ws + 5 * SZH);
        f32x2* bgpk = (f32x2*)(ws + 6 * SZH);
        unsigned short* wobf = (unsigned short*)qb;

        k_wconv<<<dim3(512, 5), dim3(256), 0, stream>>>(wp, wbf);
        k_ln<<<dim3(MTOT), dim3(256), 0, stream>>>(x, lnw, lnb, xn);
        k_proj<_Float16><<<dim3(64, 40), dim3(256), 0, stream>>>(
            xn, wbf, ba, baR, (_Float16*)qb, (_Float16*)kb, (_Float16*)vb, (_Float16*)ab, (_Float16*)aRb);
        k_bg<<<dim3(MTOT), dim3(256), 0, stream>>>(xn, Wb, bb, Wg, bg, bgpk);
        k_prep16<<<dim3(MTOT * NH / 16), dim3(256), 0, stream>>>(kb);
        k_scan16<<<dim3(256), dim3(256), 0, stream>>>(qb, kb, vb, ab, aRb, bgpk, xn);
        k_cvt1<<<dim3(512), dim3(256), 0, stream>>>(Wo, wobf);
        k_out<<<dim3(64, 8), dim3(256), 0, stream>>>(xn, wobf, x, (float*)d_out);
    }
}

// Round 5
// 831.322 us; speedup vs baseline: 1.4210x; 1.4210x over previous
//
#include <hip/hip_runtime.h>
#include <hip/hip_fp16.h>

#define B_SZ 4
#define T_SEQ 2048
#define NH 16
#define HD 64
#define DMODEL 1024
#define MTOT (B_SZ * T_SEQ)   // 8192

typedef __bf16 bf16x8 __attribute__((ext_vector_type(8)));
typedef float f32x4 __attribute__((ext_vector_type(4)));
typedef float f32x2 __attribute__((ext_vector_type(2)));
typedef _Float16 f16x4 __attribute__((ext_vector_type(4)));

__device__ __forceinline__ unsigned short f2bf(float f) {
    union { float f; unsigned int i; } c; c.f = f;
    unsigned int u = c.i;
    u += 0x7fffu + ((u >> 16) & 1u);   // round-to-nearest-even
    return (unsigned short)(u >> 16);
}
__device__ __forceinline__ float sigm(float x) { return 1.f / (1.f + __expf(-x)); }

// async global->LDS DMA, 16B/lane (GEMM staging only)
__device__ __forceinline__ void dma16(const void* g, void* l) {
    __builtin_amdgcn_global_load_lds(
        (const __attribute__((address_space(1))) void*)g,
        (__attribute__((address_space(3))) void*)l, 16, 0, 0);
}

// DPP row_ror butterfly via builtin (compiler inserts hazard nops).
template <int CTRL>
__device__ __forceinline__ float dppadd(float x) {
    int v = __builtin_amdgcn_update_dpp(0, __builtin_bit_cast(int, x), CTRL, 0xf, 0xf, false);
    return x + __builtin_bit_cast(float, v);
}
__device__ __forceinline__ float rowsum16(float x) {
    x = dppadd<0x128>(x);
    x = dppadd<0x124>(x);
    x = dppadd<0x122>(x);
    x = dppadd<0x121>(x);
    return x;
}

// Three interleaved 16-lane row reductions, fused v_add_f32_dpp (1 instr per
// stage instead of mov_dpp+add). The 3-way interleave puts >=2 instructions
// between dependent stages of each chain, satisfying the VALU->DPP 2-wait-
// state source hazard without nops; the leading s_nop 1 (2 wait states)
// covers the worst-case producer scheduled immediately before the block.
__device__ __forceinline__ void rowsum3(float& a, float& b, float& c) {
    asm volatile(
        "s_nop 1\n\t"
        "v_add_f32_dpp %0, %0, %0 row_ror:8 row_mask:0xf bank_mask:0xf\n\t"
        "v_add_f32_dpp %1, %1, %1 row_ror:8 row_mask:0xf bank_mask:0xf\n\t"
        "v_add_f32_dpp %2, %2, %2 row_ror:8 row_mask:0xf bank_mask:0xf\n\t"
        "v_add_f32_dpp %0, %0, %0 row_ror:4 row_mask:0xf bank_mask:0xf\n\t"
        "v_add_f32_dpp %1, %1, %1 row_ror:4 row_mask:0xf bank_mask:0xf\n\t"
        "v_add_f32_dpp %2, %2, %2 row_ror:4 row_mask:0xf bank_mask:0xf\n\t"
        "v_add_f32_dpp %0, %0, %0 row_ror:2 row_mask:0xf bank_mask:0xf\n\t"
        "v_add_f32_dpp %1, %1, %1 row_ror:2 row_mask:0xf bank_mask:0xf\n\t"
        "v_add_f32_dpp %2, %2, %2 row_ror:2 row_mask:0xf bank_mask:0xf\n\t"
        "v_add_f32_dpp %0, %0, %0 row_ror:1 row_mask:0xf bank_mask:0xf\n\t"
        "v_add_f32_dpp %1, %1, %1 row_ror:1 row_mask:0xf bank_mask:0xf\n\t"
        "v_add_f32_dpp %2, %2, %2 row_ror:1 row_mask:0xf bank_mask:0xf"
        : "+v"(a), "+v"(b), "+v"(c));
}

// ---------------------------------------------------------------- LayerNorm
__global__ __launch_bounds__(256, 1) void k_ln(const float* __restrict__ x,
                                               const float* __restrict__ lnw,
                                               const float* __restrict__ lnb,
                                               unsigned short* __restrict__ xn) {
    const int m = blockIdx.x;
    const int t = threadIdx.x;
    float4 xv = ((const float4*)(x + (size_t)m * DMODEL))[t];
    float s = xv.x + xv.y + xv.z + xv.w;
    float s2 = xv.x * xv.x + xv.y * xv.y + xv.z * xv.z + xv.w * xv.w;
#pragma unroll
    for (int off = 32; off >= 1; off >>= 1) {
        s += __shfl_xor(s, off);
        s2 += __shfl_xor(s2, off);
    }
    __shared__ float red[8];
    const int wid = t >> 6;
    if ((t & 63) == 0) { red[wid] = s; red[4 + wid] = s2; }
    __syncthreads();
    if (t == 0) {
        float su = red[0] + red[1] + red[2] + red[3];
        float sq = red[4] + red[5] + red[6] + red[7];
        float mu = su * (1.f / DMODEL);
        float var = sq * (1.f / DMODEL) - mu * mu;
        red[0] = mu;
        red[1] = rsqrtf(var + 1e-5f);
    }
    __syncthreads();
    float mu = red[0], rstd = red[1];
    float4 w4 = ((const float4*)lnw)[t];
    float4 b4 = ((const float4*)lnb)[t];
    ushort4 o;
    o.x = f2bf((xv.x - mu) * rstd * w4.x + b4.x);
    o.y = f2bf((xv.y - mu) * rstd * w4.y + b4.y);
    o.z = f2bf((xv.z - mu) * rstd * w4.z + b4.z);
    o.w = f2bf((xv.w - mu) * rstd * w4.w + b4.w);
    ((ushort4*)(xn + (size_t)m * DMODEL))[t] = o;
}

// ------------------------------------------- fp32 -> bf16 weight conversion
struct WPtrs { const float* p0; const float* p1; const float* p2; const float* p3; const float* p4; };

__global__ __launch_bounds__(256, 1) void k_wconv(WPtrs w, unsigned short* __restrict__ dst) {
    const int plane = blockIdx.y;
    const float* src = plane == 0 ? w.p0 : plane == 1 ? w.p1 : plane == 2 ? w.p2
                                                             : plane == 3 ? w.p3 : w.p4;
    const size_t i = ((size_t)blockIdx.x * 256 + threadIdx.x) * 8;
    float4 f0 = *(const float4*)(src + i);
    float4 f1 = *(const float4*)(src + i + 4);
    uint4 o;
    o.x = (unsigned)f2bf(f0.x) | ((unsigned)f2bf(f0.y) << 16);
    o.y = (unsigned)f2bf(f0.z) | ((unsigned)f2bf(f0.w) << 16);
    o.z = (unsigned)f2bf(f1.x) | ((unsigned)f2bf(f1.y) << 16);
    o.w = (unsigned)f2bf(f1.z) | ((unsigned)f2bf(f1.w) << 16);
    *(uint4*)(dst + (size_t)plane * 1048576 + i) = o;
}

__global__ __launch_bounds__(256, 1) void k_cvt1(const float* __restrict__ src,
                                                 unsigned short* __restrict__ dst) {
    const size_t i = ((size_t)blockIdx.x * 256 + threadIdx.x) * 8;
    float4 f0 = *(const float4*)(src + i);
    float4 f1 = *(const float4*)(src + i + 4);
    uint4 o;
    o.x = (unsigned)f2bf(f0.x) | ((unsigned)f2bf(f0.y) << 16);
    o.y = (unsigned)f2bf(f0.z) | ((unsigned)f2bf(f0.w) << 16);
    o.z = (unsigned)f2bf(f1.x) | ((unsigned)f2bf(f1.y) << 16);
    o.w = (unsigned)f2bf(f1.z) | ((unsigned)f2bf(f1.w) << 16);
    *(uint4*)(dst + i) = o;
}

// ------------------------------------------------- 128x128 bf16 MFMA tile GEMM
template <int KDIM>
__device__ __forceinline__ void gemm128(const unsigned short* __restrict__ A,
                                        const unsigned short* __restrict__ Bw,
                                        int m0, int n0, f32x4 acc[4][4]) {
    __shared__ __align__(16) unsigned short sA[128 * 32];
    __shared__ __align__(16) unsigned short sB[128 * 32];

    const int t = threadIdx.x;
    const int lane = t & 63;
    const int wv = t >> 6;
    const int wm = wv >> 1, wn = wv & 1;
    const int ml = lane & 15, kq = lane >> 4;

#pragma unroll
    for (int i = 0; i < 4; i++)
#pragma unroll
        for (int j = 0; j < 4; j++) {
            f32x4 z; z[0] = 0.f; z[1] = 0.f; z[2] = 0.f; z[3] = 0.f;
            acc[i][j] = z;
        }

    const unsigned short* pA = A + (size_t)m0 * KDIM;
    const unsigned short* pB = Bw + (size_t)n0 * KDIM;
    const unsigned short* gA0 = pA + (size_t)(t >> 2) * KDIM + (t & 3) * 8;
    const unsigned short* gA1 = gA0 + (size_t)64 * KDIM;
    const unsigned short* gB0 = pB + (size_t)(t >> 2) * KDIM + (t & 3) * 8;
    const unsigned short* gB1 = gB0 + (size_t)64 * KDIM;
    unsigned short* lA0 = sA + wv * 512;
    unsigned short* lA1 = lA0 + 2048;
    unsigned short* lB0 = sB + wv * 512;
    unsigned short* lB1 = lB0 + 2048;

    for (int kb = 0; kb < KDIM / 32; kb++) {
        const int ko = kb * 32;
        dma16(gA0 + ko, lA0);
        dma16(gA1 + ko, lA1);
        dma16(gB0 + ko, lB0);
        dma16(gB1 + ko, lB1);
        __syncthreads();
        bf16x8 af[4], bfr[4];
#pragma unroll
        for (int mt = 0; mt < 4; mt++)
            af[mt] = *(const bf16x8*)&sA[(wm * 64 + mt * 16 + ml) * 32 + kq * 8];
#pragma unroll
        for (int nt = 0; nt < 4; nt++)
            bfr[nt] = *(const bf16x8*)&sB[(wn * 64 + nt * 16 + ml) * 32 + kq * 8];
#pragma unroll
        for (int mt = 0; mt < 4; mt++)
#pragma unroll
            for (int nt = 0; nt < 4; nt++)
                acc[mt][nt] = __builtin_amdgcn_mfma_f32_16x16x32_bf16(af[mt], bfr[nt], acc[mt][nt], 0, 0, 0);
        __syncthreads();
    }
}

// -------------------------------------------- fused 5-way projection GEMM
// OT = float (fp32 stream path) or _Float16 (fallback)
template <typename OT>
__global__ __launch_bounds__(256, 1) void k_proj(const unsigned short* __restrict__ xn,
                                                 const unsigned short* __restrict__ wbf,
                                                 const float* __restrict__ ba,
                                                 const float* __restrict__ baR,
                                                 OT* __restrict__ qo, OT* __restrict__ ko,
                                                 OT* __restrict__ vo, OT* __restrict__ ao,
                                                 OT* __restrict__ aRo) {
    const int m0 = blockIdx.x * 128;
    const int yt = blockIdx.y;
    const int widx = yt >> 3;
    const int n0 = (yt & 7) * 128;
    const unsigned short* W = wbf + (size_t)widx * 1048576;
    f32x4 acc[4][4];
    gemm128<1024>(xn, W, m0, n0, acc);

    OT* outp = widx == 0 ? qo : widx == 1 ? ko : widx == 2 ? vo : widx == 3 ? ao : aRo;
    const float* bias = (widx == 3) ? ba : (widx == 4) ? baR : (const float*)0;
    const int lane = threadIdx.x & 63;
    const int wv = threadIdx.x >> 6;
    const int wm = wv >> 1, wn = wv & 1;
    const int ml = lane & 15, kq = lane >> 4;
#pragma unroll
    for (int mt = 0; mt < 4; mt++)
#pragma unroll
        for (int nt = 0; nt < 4; nt++) {
            const int rowg = m0 + wm * 64 + mt * 16 + kq * 4;
            const int colg = n0 + wn * 64 + nt * 16 + ml;
            float bval = bias ? bias[colg] : 0.f;
#pragma unroll
            for (int r = 0; r < 4; r++) {
                float v = acc[mt][nt][r];
                if (widx >= 3) v = sigm(v + bval);
                outp[(size_t)(rowg + r) * DMODEL + colg] = (OT)v;
            }
        }
}

// --------------------------------------------------- beta/gamma skinny GEMM
__global__ __launch_bounds__(256, 1) void k_bg(const unsigned short* __restrict__ xn,
                                               const float* __restrict__ Wb,
                                               const float* __restrict__ bb,
                                               const float* __restrict__ Wg,
                                               const float* __restrict__ bgp,
                                               f32x2* __restrict__ bgpk) {
    const int m = blockIdx.x;
    const int t = threadIdx.x;
    const int h = t >> 4, seg = t & 15;
    const ushort4* xr = (const ushort4*)(xn + (size_t)m * DMODEL + seg * 64);
    const float4* wbr = (const float4*)(Wb + (size_t)h * DMODEL + seg * 64);
    const float4* wgr = (const float4*)(Wg + (size_t)h * DMODEL + seg * 64);
    float db = 0.f, dg = 0.f;
#pragma unroll
    for (int u = 0; u < 16; u++) {
        ushort4 a = xr[u];
        float4 w1 = wbr[u], w2 = wgr[u];
        union { unsigned int i; float f; } c0, c1, c2, c3;
        c0.i = ((unsigned int)a.x) << 16; c1.i = ((unsigned int)a.y) << 16;
        c2.i = ((unsigned int)a.z) << 16; c3.i = ((unsigned int)a.w) << 16;
        db += c0.f * w1.x + c1.f * w1.y + c2.f * w1.z + c3.f * w1.w;
        dg += c0.f * w2.x + c1.f * w2.y + c2.f * w2.z + c3.f * w2.w;
    }
#pragma unroll
    for (int off = 1; off < 16; off <<= 1) {
        db += __shfl_xor(db, off);
        dg += __shfl_xor(dg, off);
    }
    if (seg == 0) {
        f32x2 o;
        o[0] = sigm(db + bb[h]);
        o[1] = sigm(dg + bgp[h]);
        bgpk[(size_t)m * NH + h] = o;
    }
}

// ------------------------------------------- k normalization (in-place)
__global__ __launch_bounds__(256, 1) void k_prep16(__half* __restrict__ kb) {
    const int row = blockIdx.x * 16 + (threadIdx.x >> 4);
    const int tr = threadIdx.x & 15;
    const int bh = row >> 11, t = row & 2047;
    const size_t idx = ((size_t)((bh >> 4) * T_SEQ + t)) * DMODEL + (bh & 15) * 64 + tr * 4;
    f16x4 k4 = *(const f16x4*)((const __half*)kb + idx);
    float k0 = (float)k4[0], k1 = (float)k4[1], k2 = (float)k4[2], k3 = (float)k4[3];
    float ss = k0 * k0 + k1 * k1 + k2 * k2 + k3 * k3;
    ss = rowsum16(ss);
    float inv = 1.f / fmaxf(sqrtf(ss), 1e-12f);
    f16x4 o;
    o[0] = (_Float16)(k0 * inv); o[1] = (_Float16)(k1 * inv);
    o[2] = (_Float16)(k2 * inv); o[3] = (_Float16)(k3 * inv);
    *(f16x4*)(kb + idx) = o;
}

__global__ __launch_bounds__(256, 1) void k_prep32(float* __restrict__ kb) {
    const int row = blockIdx.x * 16 + (threadIdx.x >> 4);
    const int tr = threadIdx.x & 15;
    const int bh = row >> 11, t = row & 2047;
    const size_t idx = ((size_t)((bh >> 4) * T_SEQ + t)) * DMODEL + (bh & 15) * 64 + tr * 4;
    f32x4 k4 = *(const f32x4*)(kb + idx);
    float ss = k4[0] * k4[0] + k4[1] * k4[1] + k4[2] * k4[2] + k4[3] * k4[3];
    ss = rowsum16(ss);
    float inv = 1.f / fmaxf(sqrtf(ss), 1e-12f);
    f32x4 o;
    o[0] = k4[0] * inv; o[1] = k4[1] * inv; o[2] = k4[2] * inv; o[3] = k4[3] * inv;
    *(f32x4*)(kb + idx) = o;
}

// ------------------------------------------------------------- the scan, fp32
// ROUND-3 PROVEN LAYOUT (364 us): 256 blocks, 16 lanes/column, f32x4/thread,
// pure-DPP reductions. Round-4 lesson: per-step issue is dominated by fixed
// costs (reductions, loads, scalar chain), so splitting lanes/occupancy-
// doubling does NOT help; shfl_xor(16) on the critical path HURTS (LDS pipe).
// This round's only delta vs round 3: fused v_add_f32_dpp rowsum3 (halves
// reduction instruction count).
// NOTE: T_SEQ % 6 != 0 -> all o-stores guarded by s < T_SEQ (last iteration
// computes steps 2046..2051; unguarded stores would corrupt batch b+1 rows).
__global__ __launch_bounds__(256, 1) void k_scan32(const float* __restrict__ qb,
                                                   const float* __restrict__ knb,
                                                   const float* __restrict__ vb,
                                                   const float* __restrict__ ab,
                                                   const float* __restrict__ aRb,
                                                   const f32x2* __restrict__ bgpk,
                                                   unsigned short* __restrict__ ob) {
    const int blk = blockIdx.x;
    const int bh = blk & 63, cg = blk >> 6;   // XCD co-location swizzle
    const int b = bh >> 4, h = bh & 15;
    const int t = threadIdx.x;
    const int col = t >> 4, tr = t & 15;
    const int ii = cg * 16 + col;
    const int j0 = tr * 4;

    const size_t blkoff = (size_t)b * T_SEQ * DMODEL + h * 64;  // block-uniform
    const float* pq = qb + blkoff;
    const float* pk = knb + blkoff;
    const float* pa = ab + blkoff;
    const float* pr = aRb + blkoff;
    const float* pvb = vb + blkoff;
    const f32x2* pbg = bgpk + (size_t)b * T_SEQ * NH + h;
    unsigned short* obp = ob + blkoff + ii;

    f32x2 S01 = {0.f, 0.f}, S23 = {0.f, 0.f}, R01 = {0.f, 0.f}, R23 = {0.f, 0.f};

    f32x4 rk[6], rq[6], ra[6], rr[6];
    float rv[6];
    f32x2 rbg[6];

#pragma unroll
    for (int p = 0; p < 6; p++) {
        const size_t vo = (size_t)p * DMODEL;
        rk[p] = *(const f32x4*)(pk + vo + j0);
        rq[p] = *(const f32x4*)(pq + vo + j0);
        ra[p] = *(const f32x4*)(pa + vo + j0);
        rr[p] = *(const f32x4*)(pr + vo + j0);
        rv[p] = pvb[vo + ii];
        rbg[p] = pbg[(size_t)p * NH];
    }

    float oA, oB, oC;

#define SCAN_BODY32(P, ODEST)                                                       \
    {                                                                               \
        const f32x2 kn01 = {rk[P][0], rk[P][1]}, kn23 = {rk[P][2], rk[P][3]};       \
        const f32x2 a01 = {ra[P][0], ra[P][1]}, a23 = {ra[P][2], ra[P][3]};         \
        const f32x2 x01 = {rr[P][0], rr[P][1]}, x23 = {rr[P][2], rr[P][3]};         \
        const f32x2 q01 = {rq[P][0], rq[P][1]}, q23 = {rq[P][2], rq[P][3]};         \
        const float vc = rv[P];                                                     \
        const float beta = rbg[P][0], gamma = rbg[P][1];                            \
        const f32x2 Sd01 = a01 * S01, Sd23 = a23 * S23;                             \
        const f32x2 Rd01 = x01 * R01, Rd23 = x23 * R23;                             \
        const f32x2 pv2 = S01 * kn01 + S23 * kn23;                                  \
        const f32x2 kp2 = Sd01 * kn01 + Sd23 * kn23;                                \
        const f32x2 kR2 = Rd01 * kn01 + Rd23 * kn23;                                \
        float pred = pv2[0] + pv2[1];                                               \
        float kp = kp2[0] + kp2[1];                                                 \
        float kpR = kR2[0] + kR2[1];                                                \
        rowsum3(pred, kp, kpR);                                                     \
        const float rres = fminf(fmaxf(vc - pred, -1.f), 1.f);                      \
        const float cS = beta * (vc - kp);                                          \
        const float cR = gamma * (rres - kpR);                                      \
        const f32x2 cS2 = {cS, cS}, cR2 = {cR, cR};                                 \
        S01 = cS2 * kn01 + Sd01; S23 = cS2 * kn23 + Sd23;                           \
        R01 = cR2 * kn01 + Rd01; R23 = cR2 * kn23 + Rd23;                           \
        const f32x2 ov = (S01 + R01) * q01 + (S23 + R23) * q23;                     \
        ODEST = ov[0] + ov[1];                                                      \
        /* prefetch step st+P+6 into slot P (old slot value fully consumed) */      \
        {                                                                           \
            const int sp = (st + (P) + 6) & (T_SEQ - 1);                            \
            const size_t vo = (size_t)sp * DMODEL;                                  \
            rk[P] = *(const f32x4*)(pk + vo + j0);                                  \
            rq[P] = *(const f32x4*)(pq + vo + j0);                                  \
            ra[P] = *(const f32x4*)(pa + vo + j0);                                  \
            rr[P] = *(const f32x4*)(pr + vo + j0);                                  \
            rv[P] = pvb[vo + ii];                                                   \
            rbg[P] = pbg[(size_t)sp * NH];                                          \
        }                                                                           \
    }

#define FLUSH3(SBASE)                                                               \
    {                                                                               \
        rowsum3(oA, oB, oC);                                                        \
        if (tr == 0) {                                                              \
            if ((SBASE) < T_SEQ)     obp[(size_t)(SBASE) * DMODEL] = f2bf(oA);      \
            if ((SBASE) + 1 < T_SEQ) obp[(size_t)((SBASE) + 1) * DMODEL] = f2bf(oB);\
            if ((SBASE) + 2 < T_SEQ) obp[(size_t)((SBASE) + 2) * DMODEL] = f2bf(oC);\
        }                                                                           \
    }

    for (int st = 0; st < T_SEQ; st += 6) {
        SCAN_BODY32(0, oA)
        SCAN_BODY32(1, oB)
        SCAN_BODY32(2, oC)
        FLUSH3(st)
        SCAN_BODY32(3, oA)
        SCAN_BODY32(4, oB)
        SCAN_BODY32(5, oC)
        FLUSH3(st + 3)
    }
#undef SCAN_BODY32
#undef FLUSH3
}

// ------------------------------------------------------------- the scan, fp16
// Fallback path (proven 944us kernel) used if ws_size is too small for fp32
// stream planes.
__global__ __launch_bounds__(256, 1) void k_scan16(const __half* __restrict__ qb,
                                                   const __half* __restrict__ knb,
                                                   const __half* __restrict__ vb,
                                                   const __half* __restrict__ ab,
                                                   const __half* __restrict__ aRb,
                                                   const f32x2* __restrict__ bgpk,
                                                   unsigned short* __restrict__ ob) {
    const int blk = blockIdx.x;
    const int bh = blk & 63, cg = blk >> 6;
    const int b = bh >> 4, h = bh & 15;
    const int t = threadIdx.x;
    const int col = t >> 4, tr = t & 15;
    const int ii = cg * 16 + col;
    const int j0 = tr * 4;

    const size_t vecbase = ((size_t)b * T_SEQ) * DMODEL + h * 64 + j0;
    const size_t vbase = ((size_t)b * T_SEQ) * DMODEL + h * 64 + ii;
    const size_t bgbase = ((size_t)b * T_SEQ) * NH + h;

    const __half* pk = knb + vecbase;
    const __half* pq = qb + vecbase;
    const __half* pa = ab + vecbase;
    const __half* pr = aRb + vecbase;

    float S0 = 0, S1 = 0, S2 = 0, S3 = 0, R0 = 0, R1 = 0, R2 = 0, R3 = 0;

    f16x4 rk[6], rq[6], ra[6], rr[6];
    __half rv[6];
    f32x2 rbg[6];
    f32x4 fkn[6], fq[6], fa[6], fr[6];
    float fv[6];

#pragma unroll
    for (int p = 0; p < 6; p++) {
        const size_t voff = (size_t)p * DMODEL;
        rk[p] = *(const f16x4*)(pk + voff);
        rq[p] = *(const f16x4*)(pq + voff);
        ra[p] = *(const f16x4*)(pa + voff);
        rr[p] = *(const f16x4*)(pr + voff);
        rv[p] = vb[vbase + voff];
        rbg[p] = bgpk[bgbase + (size_t)p * NH];
    }
    fkn[0][0] = (float)rk[0][0]; fkn[0][1] = (float)rk[0][1]; fkn[0][2] = (float)rk[0][2]; fkn[0][3] = (float)rk[0][3];
    fq[0][0] = (float)rq[0][0]; fq[0][1] = (float)rq[0][1]; fq[0][2] = (float)rq[0][2]; fq[0][3] = (float)rq[0][3];
    fa[0][0] = (float)ra[0][0]; fa[0][1] = (float)ra[0][1]; fa[0][2] = (float)ra[0][2]; fa[0][3] = (float)ra[0][3];
    fr[0][0] = (float)rr[0][0]; fr[0][1] = (float)rr[0][1]; fr[0][2] = (float)rr[0][2]; fr[0][3] = (float)rr[0][3];
    fv[0] = (float)rv[0];

#define SCAN_BODY(P, PN)                                                              \
    {                                                                                 \
        const int s = st + (P);                                                       \
        const float beta = rbg[P][0], gamma = rbg[P][1];                              \
        {                                                                             \
            const size_t voff = (size_t)((s + 6) & (T_SEQ - 1)) * DMODEL;             \
            rk[P] = *(const f16x4*)(pk + voff);                                       \
            rq[P] = *(const f16x4*)(pq + voff);                                       \
            ra[P] = *(const f16x4*)(pa + voff);                                       \
            rr[P] = *(const f16x4*)(pr + voff);                                       \
            rv[P] = vb[vbase + voff];                                                 \
        }                                                                             \
        fkn[PN][0] = (float)rk[PN][0]; fkn[PN][1] = (float)rk[PN][1];                 \
        fkn[PN][2] = (float)rk[PN][2]; fkn[PN][3] = (float)rk[PN][3];                 \
        fq[PN][0] = (float)rq[PN][0]; fq[PN][1] = (float)rq[PN][1];                   \
        fq[PN][2] = (float)rq[PN][2]; fq[PN][3] = (float)rq[PN][3];                   \
        fa[PN][0] = (float)ra[PN][0]; fa[PN][1] = (float)ra[PN][1];                   \
        fa[PN][2] = (float)ra[PN][2]; fa[PN][3] = (float)ra[PN][3];                   \
        fr[PN][0] = (float)rr[PN][0]; fr[PN][1] = (float)rr[PN][1];                   \
        fr[PN][2] = (float)rr[PN][2]; fr[PN][3] = (float)rr[PN][3];                   \
        fv[PN] = (float)rv[PN];                                                       \
        {                                                                             \
            const float kn0 = fkn[P][0], kn1 = fkn[P][1], kn2 = fkn[P][2], kn3 = fkn[P][3]; \
            const float a0 = fa[P][0], a1 = fa[P][1], a2 = fa[P][2], a3 = fa[P][3];   \
            const float x0 = fr[P][0], x1 = fr[P][1], x2 = fr[P][2], x3 = fr[P][3];   \
            const float vc = fv[P];                                                   \
            float pred = S0 * kn0 + S1 * kn1 + S2 * kn2 + S3 * kn3;                   \
            float Sd0 = a0 * S0, Sd1 = a1 * S1, Sd2 = a2 * S2, Sd3 = a3 * S3;         \
            float Rd0 = x0 * R0, Rd1 = x1 * R1, Rd2 = x2 * R2, Rd3 = x3 * R3;         \
            float kp = Sd0 * kn0 + Sd1 * kn1 + Sd2 * kn2 + Sd3 * kn3;                 \
            float kpR = Rd0 * kn0 + Rd1 * kn1 + Rd2 * kn2 + Rd3 * kn3;                \
            pred = rowsum16(pred);                                                    \
            kp = rowsum16(kp);                                                        \
            kpR = rowsum16(kpR);                                                      \
            const float rres = fminf(fmaxf(vc - pred, -1.f), 1.f);                    \
            const float cS = beta * (vc - kp);                                        \
            const float cR = gamma * (rres - kpR);                                    \
            S0 = fmaf(cS, kn0, Sd0); S1 = fmaf(cS, kn1, Sd1);                         \
            S2 = fmaf(cS, kn2, Sd2); S3 = fmaf(cS, kn3, Sd3);                         \
            R0 = fmaf(cR, kn0, Rd0); R1 = fmaf(cR, kn1, Rd1);                         \
            R2 = fmaf(cR, kn2, Rd2); R3 = fmaf(cR, kn3, Rd3);                         \
            float o = (S0 + R0) * fq[P][0] + (S1 + R1) * fq[P][1] +                   \
                      (S2 + R2) * fq[P][2] + (S3 + R3) * fq[P][3];                    \
            o = rowsum16(o);                                                          \
            if (tr == 0 && s < T_SEQ)                                                 \
                ob[vbase + (size_t)s * DMODEL] = f2bf(o);                             \
        }                                                                             \
        rbg[P] = bgpk[bgbase + (size_t)((s + 6) & (T_SEQ - 1)) * NH];                 \
    }

    for (int st = 0; st < T_SEQ; st += 6) {
        SCAN_BODY(0, 1)
        SCAN_BODY(1, 2)
        SCAN_BODY(2, 3)
        SCAN_BODY(3, 4)
        SCAN_BODY(4, 5)
        SCAN_BODY(5, 0)
    }
#undef SCAN_BODY
}

// ---------------------------------------------------- output GEMM + residual
__global__ __launch_bounds__(256, 1) void k_out(const unsigned short* __restrict__ ob,
                                                const unsigned short* __restrict__ wobf,
                                                const float* __restrict__ x,
                                                float* __restrict__ out) {
    const int m0 = blockIdx.x * 128;
    const int n0 = blockIdx.y * 128;
    f32x4 acc[4][4];
    gemm128<1024>(ob, wobf, m0, n0, acc);
    const int lane = threadIdx.x & 63;
    const int wv = threadIdx.x >> 6;
    const int wm = wv >> 1, wn = wv & 1;
    const int ml = lane & 15, kq = lane >> 4;
#pragma unroll
    for (int mt = 0; mt < 4; mt++)
#pragma unroll
        for (int nt = 0; nt < 4; nt++) {
            const int rowg = m0 + wm * 64 + mt * 16 + kq * 4;
            const int colg = n0 + wn * 64 + nt * 16 + ml;
#pragma unroll
            for (int r = 0; r < 4; r++) {
                size_t idx = (size_t)(rowg + r) * DMODEL + colg;
                out[idx] = acc[mt][nt][r] + x[idx];
            }
        }
}

extern "C" void kernel_launch(void* const* d_in, const int* in_sizes, int n_in,
                              void* d_out, int out_size, void* d_ws, size_t ws_size,
                              hipStream_t stream) {
    const float* x = (const float*)d_in[0];
    const float* Wq = (const float*)d_in[1];
    const float* Wk = (const float*)d_in[2];
    const float* Wv = (const float*)d_in[3];
    const float* Wa = (const float*)d_in[4];
    const float* ba = (const float*)d_in[5];
    const float* Wb = (const float*)d_in[6];
    const float* bb = (const float*)d_in[7];
    const float* Wg = (const float*)d_in[8];
    const float* bg = (const float*)d_in[9];
    const float* WaR = (const float*)d_in[10];
    const float* baR = (const float*)d_in[11];
    const float* Wo = (const float*)d_in[12];
    const float* lnw = (const float*)d_in[13];
    const float* lnb = (const float*)d_in[14];

    const size_t SZH = 16777216ULL;   // fp16/bf16 plane bytes (8192*1024*2)
    const size_t SZF = 33554432ULL;   // fp32 plane bytes (8192*1024*4)
    const size_t need32 = 5 * SZF + SZH + 2097152ULL;   // ~178 MB
    const size_t need16 = 6 * SZH + 2097152ULL;         // ~98 MB

    char* ws = (char*)d_ws;
    // d_out doubles as scratch for bf16 projection weights (10 MB of 32 MB);
    // only read by k_proj, fully overwritten by k_out at the end.
    unsigned short* wbf = (unsigned short*)d_out;
    WPtrs wp{Wq, Wk, Wv, Wa, WaR};

    if (ws_size >= need32) {
        // ---------------- fp32 stream path ----------------
        float* qb = (float*)(ws + 0 * SZF);
        float* kb = (float*)(ws + 1 * SZF);
        float* vb = (float*)(ws + 2 * SZF);
        float* ab = (float*)(ws + 3 * SZF);
        float* aRb = (float*)(ws + 4 * SZF);
        unsigned short* xn = (unsigned short*)(ws + 5 * SZF);   // bf16; reused for o
        f32x2* bgpk = (f32x2*)(ws + 5 * SZF + SZH);
        unsigned short* wobf = (unsigned short*)qb;             // qb dead after scan

        k_wconv<<<dim3(512, 5), dim3(256), 0, stream>>>(wp, wbf);
        k_ln<<<dim3(MTOT), dim3(256), 0, stream>>>(x, lnw, lnb, xn);
        k_proj<float><<<dim3(64, 40), dim3(256), 0, stream>>>(xn, wbf, ba, baR, qb, kb, vb, ab, aRb);
        k_bg<<<dim3(MTOT), dim3(256), 0, stream>>>(xn, Wb, bb, Wg, bg, bgpk);
        k_prep32<<<dim3(MTOT * NH / 16), dim3(256), 0, stream>>>(kb);
        k_scan32<<<dim3(256), dim3(256), 0, stream>>>(qb, kb, vb, ab, aRb, bgpk, xn);
        k_cvt1<<<dim3(512), dim3(256), 0, stream>>>(Wo, wobf);
        k_out<<<dim3(64, 8), dim3(256), 0, stream>>>(xn, wobf, x, (float*)d_out);
    } else if (ws_size >= need16) {
        // ---------------- fp16 fallback (previous proven path) ----------------
        __half* qb = (__half*)(ws + 0 * SZH);
        __half* kb = (__half*)(ws + 1 * SZH);
        __half* vb = (__half*)(ws + 2 * SZH);
        __half* ab = (__half*)(ws + 3 * SZH);
        __half* aRb = (__half*)(ws + 4 * SZH);
        unsigned short* xn = (unsigned short*)(ws + 5 * SZH);
        f32x2* bgpk = (f32x2*)(ws + 6 * SZH);
        unsigned short* wobf = (unsigned short*)qb;

        k_wconv<<<dim3(512, 5), dim3(256), 0, stream>>>(wp, wbf);
        k_ln<<<dim3(MTOT), dim3(256), 0, stream>>>(x, lnw, lnb, xn);
        k_proj<_Float16><<<dim3(64, 40), dim3(256), 0, stream>>>(
            xn, wbf, ba, baR, (_Float16*)qb, (_Float16*)kb, (_Float16*)vb, (_Float16*)ab, (_Float16*)aRb);
        k_bg<<<dim3(MTOT), dim3(256), 0, stream>>>(xn, Wb, bb, Wg, bg, bgpk);
        k_prep16<<<dim3(MTOT * NH / 16), dim3(256), 0, stream>>>(kb);
        k_scan16<<<dim3(256), dim3(256), 0, stream>>>(qb, kb, vb, ab, aRb, bgpk, xn);
        k_cvt1<<<dim3(512), dim3(256), 0, stream>>>(Wo, wobf);
        k_out<<<dim3(64, 8), dim3(256), 0, stream>>>(xn, wobf, x, (float*)d_out);
    }
}

// Round 6
// 826.077 us; speedup vs baseline: 1.4300x; 1.0063x over previous
//
#include <hip/hip_runtime.h>
#include <hip/hip_fp16.h>

#define B_SZ 4
#define T_SEQ 2048
#define NH 16
#define HD 64
#define DMODEL 1024
#define MTOT (B_SZ * T_SEQ)   // 8192

typedef __bf16 bf16x8 __attribute__((ext_vector_type(8)));
typedef float f32x4 __attribute__((ext_vector_type(4)));
typedef float f32x2 __attribute__((ext_vector_type(2)));
typedef _Float16 f16x4 __attribute__((ext_vector_type(4)));

__device__ __forceinline__ unsigned short f2bf(float f) {
    union { float f; unsigned int i; } c; c.f = f;
    unsigned int u = c.i;
    u += 0x7fffu + ((u >> 16) & 1u);   // round-to-nearest-even
    return (unsigned short)(u >> 16);
}
__device__ __forceinline__ float sigm(float x) { return 1.f / (1.f + __expf(-x)); }

// async global->LDS DMA, 16B/lane (GEMM staging only)
__device__ __forceinline__ void dma16(const void* g, void* l) {
    __builtin_amdgcn_global_load_lds(
        (const __attribute__((address_space(1))) void*)g,
        (__attribute__((address_space(3))) void*)l, 16, 0, 0);
}

// DPP row_ror butterfly via builtin (compiler inserts hazard nops).
template <int CTRL>
__device__ __forceinline__ float dppadd(float x) {
    int v = __builtin_amdgcn_update_dpp(0, __builtin_bit_cast(int, x), CTRL, 0xf, 0xf, false);
    return x + __builtin_bit_cast(float, v);
}
__device__ __forceinline__ float rowsum16(float x) {
    x = dppadd<0x128>(x);
    x = dppadd<0x124>(x);
    x = dppadd<0x122>(x);
    x = dppadd<0x121>(x);
    return x;
}

// Three interleaved 16-lane row reductions, fused v_add_f32_dpp (1 instr per
// stage). The 3-way interleave puts >=2 instructions between dependent stages
// of each chain (VALU->DPP hazard); leading s_nop 1 covers the producers.
__device__ __forceinline__ void rowsum3(float& a, float& b, float& c) {
    asm volatile(
        "s_nop 1\n\t"
        "v_add_f32_dpp %0, %0, %0 row_ror:8 row_mask:0xf bank_mask:0xf\n\t"
        "v_add_f32_dpp %1, %1, %1 row_ror:8 row_mask:0xf bank_mask:0xf\n\t"
        "v_add_f32_dpp %2, %2, %2 row_ror:8 row_mask:0xf bank_mask:0xf\n\t"
        "v_add_f32_dpp %0, %0, %0 row_ror:4 row_mask:0xf bank_mask:0xf\n\t"
        "v_add_f32_dpp %1, %1, %1 row_ror:4 row_mask:0xf bank_mask:0xf\n\t"
        "v_add_f32_dpp %2, %2, %2 row_ror:4 row_mask:0xf bank_mask:0xf\n\t"
        "v_add_f32_dpp %0, %0, %0 row_ror:2 row_mask:0xf bank_mask:0xf\n\t"
        "v_add_f32_dpp %1, %1, %1 row_ror:2 row_mask:0xf bank_mask:0xf\n\t"
        "v_add_f32_dpp %2, %2, %2 row_ror:2 row_mask:0xf bank_mask:0xf\n\t"
        "v_add_f32_dpp %0, %0, %0 row_ror:1 row_mask:0xf bank_mask:0xf\n\t"
        "v_add_f32_dpp %1, %1, %1 row_ror:1 row_mask:0xf bank_mask:0xf\n\t"
        "v_add_f32_dpp %2, %2, %2 row_ror:1 row_mask:0xf bank_mask:0xf"
        : "+v"(a), "+v"(b), "+v"(c));
}

// ---------------------------------------------------------------- LayerNorm
__global__ __launch_bounds__(256, 1) void k_ln(const float* __restrict__ x,
                                               const float* __restrict__ lnw,
                                               const float* __restrict__ lnb,
                                               unsigned short* __restrict__ xn) {
    const int m = blockIdx.x;
    const int t = threadIdx.x;
    float4 xv = ((const float4*)(x + (size_t)m * DMODEL))[t];
    float s = xv.x + xv.y + xv.z + xv.w;
    float s2 = xv.x * xv.x + xv.y * xv.y + xv.z * xv.z + xv.w * xv.w;
#pragma unroll
    for (int off = 32; off >= 1; off >>= 1) {
        s += __shfl_xor(s, off);
        s2 += __shfl_xor(s2, off);
    }
    __shared__ float red[8];
    const int wid = t >> 6;
    if ((t & 63) == 0) { red[wid] = s; red[4 + wid] = s2; }
    __syncthreads();
    if (t == 0) {
        float su = red[0] + red[1] + red[2] + red[3];
        float sq = red[4] + red[5] + red[6] + red[7];
        float mu = su * (1.f / DMODEL);
        float var = sq * (1.f / DMODEL) - mu * mu;
        red[0] = mu;
        red[1] = rsqrtf(var + 1e-5f);
    }
    __syncthreads();
    float mu = red[0], rstd = red[1];
    float4 w4 = ((const float4*)lnw)[t];
    float4 b4 = ((const float4*)lnb)[t];
    ushort4 o;
    o.x = f2bf((xv.x - mu) * rstd * w4.x + b4.x);
    o.y = f2bf((xv.y - mu) * rstd * w4.y + b4.y);
    o.z = f2bf((xv.z - mu) * rstd * w4.z + b4.z);
    o.w = f2bf((xv.w - mu) * rstd * w4.w + b4.w);
    ((ushort4*)(xn + (size_t)m * DMODEL))[t] = o;
}

// ------------------------------------------- fp32 -> bf16 weight conversion
struct WPtrs { const float* p0; const float* p1; const float* p2; const float* p3; const float* p4; };

__global__ __launch_bounds__(256, 1) void k_wconv(WPtrs w, unsigned short* __restrict__ dst) {
    const int plane = blockIdx.y;
    const float* src = plane == 0 ? w.p0 : plane == 1 ? w.p1 : plane == 2 ? w.p2
                                                             : plane == 3 ? w.p3 : w.p4;
    const size_t i = ((size_t)blockIdx.x * 256 + threadIdx.x) * 8;
    float4 f0 = *(const float4*)(src + i);
    float4 f1 = *(const float4*)(src + i + 4);
    uint4 o;
    o.x = (unsigned)f2bf(f0.x) | ((unsigned)f2bf(f0.y) << 16);
    o.y = (unsigned)f2bf(f0.z) | ((unsigned)f2bf(f0.w) << 16);
    o.z = (unsigned)f2bf(f1.x) | ((unsigned)f2bf(f1.y) << 16);
    o.w = (unsigned)f2bf(f1.z) | ((unsigned)f2bf(f1.w) << 16);
    *(uint4*)(dst + (size_t)plane * 1048576 + i) = o;
}

__global__ __launch_bounds__(256, 1) void k_cvt1(const float* __restrict__ src,
                                                 unsigned short* __restrict__ dst) {
    const size_t i = ((size_t)blockIdx.x * 256 + threadIdx.x) * 8;
    float4 f0 = *(const float4*)(src + i);
    float4 f1 = *(const float4*)(src + i + 4);
    uint4 o;
    o.x = (unsigned)f2bf(f0.x) | ((unsigned)f2bf(f0.y) << 16);
    o.y = (unsigned)f2bf(f0.z) | ((unsigned)f2bf(f0.w) << 16);
    o.z = (unsigned)f2bf(f1.x) | ((unsigned)f2bf(f1.y) << 16);
    o.w = (unsigned)f2bf(f1.z) | ((unsigned)f2bf(f1.w) << 16);
    *(uint4*)(dst + i) = o;
}

// ------------------------------------------------- 128x128 bf16 MFMA tile GEMM
// Double-buffered 2-phase pipeline (guide T3-minimal): stage tile kb+1 into
// buf^1 BEFORE computing tile kb; one raw s_barrier per K-step with explicit
// s_waitcnt (the compiler's __syncthreads would drain vmcnt(0) and kill the
// prefetch overlap). Correctness: vmcnt(0)+lgkmcnt(0)+barrier at iteration end
// guarantees (a) this iter's prefetch landed before anyone reads buf^1, and
// (b) all waves' ds_reads of buf[cur] completed before next iter's dma16
// overwrites it two steps later. MFMA sinking past the asm is benign
// (register-only operands).
template <int KDIM>
__device__ __forceinline__ void gemm128(const unsigned short* __restrict__ A,
                                        const unsigned short* __restrict__ Bw,
                                        int m0, int n0, f32x4 acc[4][4]) {
    __shared__ __align__(16) unsigned short sA[2 * 128 * 32];
    __shared__ __align__(16) unsigned short sB[2 * 128 * 32];

    const int t = threadIdx.x;
    const int lane = t & 63;
    const int wv = t >> 6;
    const int wm = wv >> 1, wn = wv & 1;
    const int ml = lane & 15, kq = lane >> 4;

#pragma unroll
    for (int i = 0; i < 4; i++)
#pragma unroll
        for (int j = 0; j < 4; j++) {
            f32x4 z; z[0] = 0.f; z[1] = 0.f; z[2] = 0.f; z[3] = 0.f;
            acc[i][j] = z;
        }

    const unsigned short* pA = A + (size_t)m0 * KDIM;
    const unsigned short* pB = Bw + (size_t)n0 * KDIM;
    const unsigned short* gA0 = pA + (size_t)(t >> 2) * KDIM + (t & 3) * 8;
    const unsigned short* gA1 = gA0 + (size_t)64 * KDIM;
    const unsigned short* gB0 = pB + (size_t)(t >> 2) * KDIM + (t & 3) * 8;
    const unsigned short* gB1 = gB0 + (size_t)64 * KDIM;
    unsigned short* lA0 = sA + wv * 512;
    unsigned short* lA1 = lA0 + 2048;
    unsigned short* lB0 = sB + wv * 512;
    unsigned short* lB1 = lB0 + 2048;

    constexpr int NK = KDIM / 32;

    // prologue: stage tile 0 into buffer 0
    dma16(gA0, lA0);
    dma16(gA1, lA1);
    dma16(gB0, lB0);
    dma16(gB1, lB1);
    asm volatile("s_waitcnt vmcnt(0)" ::: "memory");
    __builtin_amdgcn_s_barrier();

    int cur = 0;
    for (int kb = 0; kb < NK; kb++) {
        const int nxt = cur ^ 1;
        // issue next tile's staging first (overlaps with ds_read + MFMA below)
        if (kb + 1 < NK) {
            const int ko = (kb + 1) * 32;
            const int bo = nxt * 4096;
            dma16(gA0 + ko, lA0 + bo);
            dma16(gA1 + ko, lA1 + bo);
            dma16(gB0 + ko, lB0 + bo);
            dma16(gB1 + ko, lB1 + bo);
        }
        const unsigned short* bA = sA + cur * 4096;
        const unsigned short* bB = sB + cur * 4096;
        bf16x8 af[4], bfr[4];
#pragma unroll
        for (int mt = 0; mt < 4; mt++)
            af[mt] = *(const bf16x8*)&bA[(wm * 64 + mt * 16 + ml) * 32 + kq * 8];
#pragma unroll
        for (int nt = 0; nt < 4; nt++)
            bfr[nt] = *(const bf16x8*)&bB[(wn * 64 + nt * 16 + ml) * 32 + kq * 8];
#pragma unroll
        for (int mt = 0; mt < 4; mt++)
#pragma unroll
            for (int nt = 0; nt < 4; nt++)
                acc[mt][nt] = __builtin_amdgcn_mfma_f32_16x16x32_bf16(af[mt], bfr[nt], acc[mt][nt], 0, 0, 0);
        // drain this iter's prefetch (vm) and our ds_reads (lgkm), then barrier
        asm volatile("s_waitcnt vmcnt(0) lgkmcnt(0)" ::: "memory");
        __builtin_amdgcn_s_barrier();
        cur = nxt;
    }
}

// -------------------------------------------- fused 5-way projection GEMM
// OT = float (fp32 stream path) or _Float16 (fallback)
template <typename OT>
__global__ __launch_bounds__(256, 1) void k_proj(const unsigned short* __restrict__ xn,
                                                 const unsigned short* __restrict__ wbf,
                                                 const float* __restrict__ ba,
                                                 const float* __restrict__ baR,
                                                 OT* __restrict__ qo, OT* __restrict__ ko,
                                                 OT* __restrict__ vo, OT* __restrict__ ao,
                                                 OT* __restrict__ aRo) {
    const int m0 = blockIdx.x * 128;
    const int yt = blockIdx.y;
    const int widx = yt >> 3;
    const int n0 = (yt & 7) * 128;
    const unsigned short* W = wbf + (size_t)widx * 1048576;
    f32x4 acc[4][4];
    gemm128<1024>(xn, W, m0, n0, acc);

    OT* outp = widx == 0 ? qo : widx == 1 ? ko : widx == 2 ? vo : widx == 3 ? ao : aRo;
    const float* bias = (widx == 3) ? ba : (widx == 4) ? baR : (const float*)0;
    const int lane = threadIdx.x & 63;
    const int wv = threadIdx.x >> 6;
    const int wm = wv >> 1, wn = wv & 1;
    const int ml = lane & 15, kq = lane >> 4;
#pragma unroll
    for (int mt = 0; mt < 4; mt++)
#pragma unroll
        for (int nt = 0; nt < 4; nt++) {
            const int rowg = m0 + wm * 64 + mt * 16 + kq * 4;
            const int colg = n0 + wn * 64 + nt * 16 + ml;
            float bval = bias ? bias[colg] : 0.f;
#pragma unroll
            for (int r = 0; r < 4; r++) {
                float v = acc[mt][nt][r];
                if (widx >= 3) v = sigm(v + bval);
                outp[(size_t)(rowg + r) * DMODEL + colg] = (OT)v;
            }
        }
}

// --------------------------------------------------- beta/gamma skinny GEMM
__global__ __launch_bounds__(256, 1) void k_bg(const unsigned short* __restrict__ xn,
                                               const float* __restrict__ Wb,
                                               const float* __restrict__ bb,
                                               const float* __restrict__ Wg,
                                               const float* __restrict__ bgp,
                                               f32x2* __restrict__ bgpk) {
    const int m = blockIdx.x;
    const int t = threadIdx.x;
    const int h = t >> 4, seg = t & 15;
    const ushort4* xr = (const ushort4*)(xn + (size_t)m * DMODEL + seg * 64);
    const float4* wbr = (const float4*)(Wb + (size_t)h * DMODEL + seg * 64);
    const float4* wgr = (const float4*)(Wg + (size_t)h * DMODEL + seg * 64);
    float db = 0.f, dg = 0.f;
#pragma unroll
    for (int u = 0; u < 16; u++) {
        ushort4 a = xr[u];
        float4 w1 = wbr[u], w2 = wgr[u];
        union { unsigned int i; float f; } c0, c1, c2, c3;
        c0.i = ((unsigned int)a.x) << 16; c1.i = ((unsigned int)a.y) << 16;
        c2.i = ((unsigned int)a.z) << 16; c3.i = ((unsigned int)a.w) << 16;
        db += c0.f * w1.x + c1.f * w1.y + c2.f * w1.z + c3.f * w1.w;
        dg += c0.f * w2.x + c1.f * w2.y + c2.f * w2.z + c3.f * w2.w;
    }
#pragma unroll
    for (int off = 1; off < 16; off <<= 1) {
        db += __shfl_xor(db, off);
        dg += __shfl_xor(dg, off);
    }
    if (seg == 0) {
        f32x2 o;
        o[0] = sigm(db + bb[h]);
        o[1] = sigm(dg + bgp[h]);
        bgpk[(size_t)m * NH + h] = o;
    }
}

// ------------------------------------------- k normalization (in-place)
__global__ __launch_bounds__(256, 1) void k_prep16(__half* __restrict__ kb) {
    const int row = blockIdx.x * 16 + (threadIdx.x >> 4);
    const int tr = threadIdx.x & 15;
    const int bh = row >> 11, t = row & 2047;
    const size_t idx = ((size_t)((bh >> 4) * T_SEQ + t)) * DMODEL + (bh & 15) * 64 + tr * 4;
    f16x4 k4 = *(const f16x4*)((const __half*)kb + idx);
    float k0 = (float)k4[0], k1 = (float)k4[1], k2 = (float)k4[2], k3 = (float)k4[3];
    float ss = k0 * k0 + k1 * k1 + k2 * k2 + k3 * k3;
    ss = rowsum16(ss);
    float inv = 1.f / fmaxf(sqrtf(ss), 1e-12f);
    f16x4 o;
    o[0] = (_Float16)(k0 * inv); o[1] = (_Float16)(k1 * inv);
    o[2] = (_Float16)(k2 * inv); o[3] = (_Float16)(k3 * inv);
    *(f16x4*)(kb + idx) = o;
}

__global__ __launch_bounds__(256, 1) void k_prep32(float* __restrict__ kb) {
    const int row = blockIdx.x * 16 + (threadIdx.x >> 4);
    const int tr = threadIdx.x & 15;
    const int bh = row >> 11, t = row & 2047;
    const size_t idx = ((size_t)((bh >> 4) * T_SEQ + t)) * DMODEL + (bh & 15) * 64 + tr * 4;
    f32x4 k4 = *(const f32x4*)(kb + idx);
    float ss = k4[0] * k4[0] + k4[1] * k4[1] + k4[2] * k4[2] + k4[3] * k4[3];
    ss = rowsum16(ss);
    float inv = 1.f / fmaxf(sqrtf(ss), 1e-12f);
    f32x4 o;
    o[0] = k4[0] * inv; o[1] = k4[1] * inv; o[2] = k4[2] * inv; o[3] = k4[3] * inv;
    *(f32x4*)(kb + idx) = o;
}

// ------------------------------------------------------------- the scan, fp32
// ROUND-3/5 PROVEN LAYOUT (362 us): 256 blocks, 16 lanes/column, f32x4/thread,
// fused-DPP reductions. Latency-bound at 1 wave/SIMD; occupancy-doubling via
// lane-split proven NOT to help (round 4). Untouched this round.
// NOTE: T_SEQ % 6 != 0 -> all o-stores guarded by s < T_SEQ.
__global__ __launch_bounds__(256, 1) void k_scan32(const float* __restrict__ qb,
                                                   const float* __restrict__ knb,
                                                   const float* __restrict__ vb,
                                                   const float* __restrict__ ab,
                                                   const float* __restrict__ aRb,
                                                   const f32x2* __restrict__ bgpk,
                                                   unsigned short* __restrict__ ob) {
    const int blk = blockIdx.x;
    const int bh = blk & 63, cg = blk >> 6;   // XCD co-location swizzle
    const int b = bh >> 4, h = bh & 15;
    const int t = threadIdx.x;
    const int col = t >> 4, tr = t & 15;
    const int ii = cg * 16 + col;
    const int j0 = tr * 4;

    const size_t blkoff = (size_t)b * T_SEQ * DMODEL + h * 64;  // block-uniform
    const float* pq = qb + blkoff;
    const float* pk = knb + blkoff;
    const float* pa = ab + blkoff;
    const float* pr = aRb + blkoff;
    const float* pvb = vb + blkoff;
    const f32x2* pbg = bgpk + (size_t)b * T_SEQ * NH + h;
    unsigned short* obp = ob + blkoff + ii;

    f32x2 S01 = {0.f, 0.f}, S23 = {0.f, 0.f}, R01 = {0.f, 0.f}, R23 = {0.f, 0.f};

    f32x4 rk[6], rq[6], ra[6], rr[6];
    float rv[6];
    f32x2 rbg[6];

#pragma unroll
    for (int p = 0; p < 6; p++) {
        const size_t vo = (size_t)p * DMODEL;
        rk[p] = *(const f32x4*)(pk + vo + j0);
        rq[p] = *(const f32x4*)(pq + vo + j0);
        ra[p] = *(const f32x4*)(pa + vo + j0);
        rr[p] = *(const f32x4*)(pr + vo + j0);
        rv[p] = pvb[vo + ii];
        rbg[p] = pbg[(size_t)p * NH];
    }

    float oA, oB, oC;

#define SCAN_BODY32(P, ODEST)                                                       \
    {                                                                               \
        const f32x2 kn01 = {rk[P][0], rk[P][1]}, kn23 = {rk[P][2], rk[P][3]};       \
        const f32x2 a01 = {ra[P][0], ra[P][1]}, a23 = {ra[P][2], ra[P][3]};         \
        const f32x2 x01 = {rr[P][0], rr[P][1]}, x23 = {rr[P][2], rr[P][3]};         \
        const f32x2 q01 = {rq[P][0], rq[P][1]}, q23 = {rq[P][2], rq[P][3]};         \
        const float vc = rv[P];                                                     \
        const float beta = rbg[P][0], gamma = rbg[P][1];                            \
        const f32x2 Sd01 = a01 * S01, Sd23 = a23 * S23;                             \
        const f32x2 Rd01 = x01 * R01, Rd23 = x23 * R23;                             \
        const f32x2 pv2 = S01 * kn01 + S23 * kn23;                                  \
        const f32x2 kp2 = Sd01 * kn01 + Sd23 * kn23;                                \
        const f32x2 kR2 = Rd01 * kn01 + Rd23 * kn23;                                \
        float pred = pv2[0] + pv2[1];                                               \
        float kp = kp2[0] + kp2[1];                                                 \
        float kpR = kR2[0] + kR2[1];                                                \
        rowsum3(pred, kp, kpR);                                                     \
        const float rres = fminf(fmaxf(vc - pred, -1.f), 1.f);                      \
        const float cS = beta * (vc - kp);                                          \
        const float cR = gamma * (rres - kpR);                                      \
        const f32x2 cS2 = {cS, cS}, cR2 = {cR, cR};                                 \
        S01 = cS2 * kn01 + Sd01; S23 = cS2 * kn23 + Sd23;                           \
        R01 = cR2 * kn01 + Rd01; R23 = cR2 * kn23 + Rd23;                           \
        const f32x2 ov = (S01 + R01) * q01 + (S23 + R23) * q23;                     \
        ODEST = ov[0] + ov[1];                                                      \
        /* prefetch step st+P+6 into slot P (old slot value fully consumed) */      \
        {                                                                           \
            const int sp = (st + (P) + 6) & (T_SEQ - 1);                            \
            const size_t vo = (size_t)sp * DMODEL;                                  \
            rk[P] = *(const f32x4*)(pk + vo + j0);                                  \
            rq[P] = *(const f32x4*)(pq + vo + j0);                                  \
            ra[P] = *(const f32x4*)(pa + vo + j0);                                  \
            rr[P] = *(const f32x4*)(pr + vo + j0);                                  \
            rv[P] = pvb[vo + ii];                                                   \
            rbg[P] = pbg[(size_t)sp * NH];                                          \
        }                                                                           \
    }

#define FLUSH3(SBASE)                                                               \
    {                                                                               \
        rowsum3(oA, oB, oC);                                                        \
        if (tr == 0) {                                                              \
            if ((SBASE) < T_SEQ)     obp[(size_t)(SBASE) * DMODEL] = f2bf(oA);      \
            if ((SBASE) + 1 < T_SEQ) obp[(size_t)((SBASE) + 1) * DMODEL] = f2bf(oB);\
            if ((SBASE) + 2 < T_SEQ) obp[(size_t)((SBASE) + 2) * DMODEL] = f2bf(oC);\
        }                                                                           \
    }

    for (int st = 0; st < T_SEQ; st += 6) {
        SCAN_BODY32(0, oA)
        SCAN_BODY32(1, oB)
        SCAN_BODY32(2, oC)
        FLUSH3(st)
        SCAN_BODY32(3, oA)
        SCAN_BODY32(4, oB)
        SCAN_BODY32(5, oC)
        FLUSH3(st + 3)
    }
#undef SCAN_BODY32
#undef FLUSH3
}

// ------------------------------------------------------------- the scan, fp16
// Fallback path (proven 944us kernel) used if ws_size is too small for fp32
// stream planes.
__global__ __launch_bounds__(256, 1) void k_scan16(const __half* __restrict__ qb,
                                                   const __half* __restrict__ knb,
                                                   const __half* __restrict__ vb,
                                                   const __half* __restrict__ ab,
                                                   const __half* __restrict__ aRb,
                                                   const f32x2* __restrict__ bgpk,
                                                   unsigned short* __restrict__ ob) {
    const int blk = blockIdx.x;
    const int bh = blk & 63, cg = blk >> 6;
    const int b = bh >> 4, h = bh & 15;
    const int t = threadIdx.x;
    const int col = t >> 4, tr = t & 15;
    const int ii = cg * 16 + col;
    const int j0 = tr * 4;

    const size_t vecbase = ((size_t)b * T_SEQ) * DMODEL + h * 64 + j0;
    const size_t vbase = ((size_t)b * T_SEQ) * DMODEL + h * 64 + ii;
    const size_t bgbase = ((size_t)b * T_SEQ) * NH + h;

    const __half* pk = knb + vecbase;
    const __half* pq = qb + vecbase;
    const __half* pa = ab + vecbase;
    const __half* pr = aRb + vecbase;

    float S0 = 0, S1 = 0, S2 = 0, S3 = 0, R0 = 0, R1 = 0, R2 = 0, R3 = 0;

    f16x4 rk[6], rq[6], ra[6], rr[6];
    __half rv[6];
    f32x2 rbg[6];
    f32x4 fkn[6], fq[6], fa[6], fr[6];
    float fv[6];

#pragma unroll
    for (int p = 0; p < 6; p++) {
        const size_t voff = (size_t)p * DMODEL;
        rk[p] = *(const f16x4*)(pk + voff);
        rq[p] = *(const f16x4*)(pq + voff);
        ra[p] = *(const f16x4*)(pa + voff);
        rr[p] = *(const f16x4*)(pr + voff);
        rv[p] = vb[vbase + voff];
        rbg[p] = bgpk[bgbase + (size_t)p * NH];
    }
    fkn[0][0] = (float)rk[0][0]; fkn[0][1] = (float)rk[0][1]; fkn[0][2] = (float)rk[0][2]; fkn[0][3] = (float)rk[0][3];
    fq[0][0] = (float)rq[0][0]; fq[0][1] = (float)rq[0][1]; fq[0][2] = (float)rq[0][2]; fq[0][3] = (float)rq[0][3];
    fa[0][0] = (float)ra[0][0]; fa[0][1] = (float)ra[0][1]; fa[0][2] = (float)ra[0][2]; fa[0][3] = (float)ra[0][3];
    fr[0][0] = (float)rr[0][0]; fr[0][1] = (float)rr[0][1]; fr[0][2] = (float)rr[0][2]; fr[0][3] = (float)rr[0][3];
    fv[0] = (float)rv[0];

#define SCAN_BODY(P, PN)                                                              \
    {                                                                                 \
        const int s = st + (P);                                                       \
        const float beta = rbg[P][0], gamma = rbg[P][1];                              \
        {                                                                             \
            const size_t voff = (size_t)((s + 6) & (T_SEQ - 1)) * DMODEL;             \
            rk[P] = *(const f16x4*)(pk + voff);                                       \
            rq[P] = *(const f16x4*)(pq + voff);                                       \
            ra[P] = *(const f16x4*)(pa + voff);                                       \
            rr[P] = *(const f16x4*)(pr + voff);                                       \
            rv[P] = vb[vbase + voff];                                                 \
        }                                                                             \
        fkn[PN][0] = (float)rk[PN][0]; fkn[PN][1] = (float)rk[PN][1];                 \
        fkn[PN][2] = (float)rk[PN][2]; fkn[PN][3] = (float)rk[PN][3];                 \
        fq[PN][0] = (float)rq[PN][0]; fq[PN][1] = (float)rq[PN][1];                   \
        fq[PN][2] = (float)rq[PN][2]; fq[PN][3] = (float)rq[PN][3];                   \
        fa[PN][0] = (float)ra[PN][0]; fa[PN][1] = (float)ra[PN][1];                   \
        fa[PN][2] = (float)ra[PN][2]; fa[PN][3] = (float)ra[PN][3];                   \
        fr[PN][0] = (float)rr[PN][0]; fr[PN][1] = (float)rr[PN][1];                   \
        fr[PN][2] = (float)rr[PN][2]; fr[PN][3] = (float)rr[PN][3];                   \
        fv[PN] = (float)rv[PN];                                                       \
        {                                                                             \
            const float kn0 = fkn[P][0], kn1 = fkn[P][1], kn2 = fkn[P][2], kn3 = fkn[P][3]; \
            const float a0 = fa[P][0], a1 = fa[P][1], a2 = fa[P][2], a3 = fa[P][3];   \
            const float x0 = fr[P][0], x1 = fr[P][1], x2 = fr[P][2], x3 = fr[P][3];   \
            const float vc = fv[P];                                                   \
            float pred = S0 * kn0 + S1 * kn1 + S2 * kn2 + S3 * kn3;                   \
            float Sd0 = a0 * S0, Sd1 = a1 * S1, Sd2 = a2 * S2, Sd3 = a3 * S3;         \
            float Rd0 = x0 * R0, Rd1 = x1 * R1, Rd2 = x2 * R2, Rd3 = x3 * R3;         \
            float kp = Sd0 * kn0 + Sd1 * kn1 + Sd2 * kn2 + Sd3 * kn3;                 \
            float kpR = Rd0 * kn0 + Rd1 * kn1 + Rd2 * kn2 + Rd3 * kn3;                \
            pred = rowsum16(pred);                                                    \
            kp = rowsum16(kp);                                                        \
            kpR = rowsum16(kpR);                                                      \
            const float rres = fminf(fmaxf(vc - pred, -1.f), 1.f);                    \
            const float cS = beta * (vc - kp);                                        \
            const float cR = gamma * (rres - kpR);                                    \
            S0 = fmaf(cS, kn0, Sd0); S1 = fmaf(cS, kn1, Sd1);                         \
            S2 = fmaf(cS, kn2, Sd2); S3 = fmaf(cS, kn3, Sd3);                         \
            R0 = fmaf(cR, kn0, Rd0); R1 = fmaf(cR, kn1, Rd1);                         \
            R2 = fmaf(cR, kn2, Rd2); R3 = fmaf(cR, kn3, Rd3);                         \
            float o = (S0 + R0) * fq[P][0] + (S1 + R1) * fq[P][1] +                   \
                      (S2 + R2) * fq[P][2] + (S3 + R3) * fq[P][3];                    \
            o = rowsum16(o);                                                          \
            if (tr == 0 && s < T_SEQ)                                                 \
                ob[vbase + (size_t)s * DMODEL] = f2bf(o);                             \
        }                                                                             \
        rbg[P] = bgpk[bgbase + (size_t)((s + 6) & (T_SEQ - 1)) * NH];                 \
    }

    for (int st = 0; st < T_SEQ; st += 6) {
        SCAN_BODY(0, 1)
        SCAN_BODY(1, 2)
        SCAN_BODY(2, 3)
        SCAN_BODY(3, 4)
        SCAN_BODY(4, 5)
        SCAN_BODY(5, 0)
    }
#undef SCAN_BODY
}

// ---------------------------------------------------- output GEMM + residual
__global__ __launch_bounds__(256, 1) void k_out(const unsigned short* __restrict__ ob,
                                                const unsigned short* __restrict__ wobf,
                                                const float* __restrict__ x,
                                                float* __restrict__ out) {
    const int m0 = blockIdx.x * 128;
    const int n0 = blockIdx.y * 128;
    f32x4 acc[4][4];
    gemm128<1024>(ob, wobf, m0, n0, acc);
    const int lane = threadIdx.x & 63;
    const int wv = threadIdx.x >> 6;
    const int wm = wv >> 1, wn = wv & 1;
    const int ml = lane & 15, kq = lane >> 4;
#pragma unroll
    for (int mt = 0; mt < 4; mt++)
#pragma unroll
        for (int nt = 0; nt < 4; nt++) {
            const int rowg = m0 + wm * 64 + mt * 16 + kq * 4;
            const int colg = n0 + wn * 64 + nt * 16 + ml;
#pragma unroll
            for (int r = 0; r < 4; r++) {
                size_t idx = (size_t)(rowg + r) * DMODEL + colg;
                out[idx] = acc[mt][nt][r] + x[idx];
            }
        }
}

extern "C" void kernel_launch(void* const* d_in, const int* in_sizes, int n_in,
                              void* d_out, int out_size, void* d_ws, size_t ws_size,
                              hipStream_t stream) {
    const float* x = (const float*)d_in[0];
    const float* Wq = (const float*)d_in[1];
    const float* Wk = (const float*)d_in[2];
    const float* Wv = (const float*)d_in[3];
    const float* Wa = (const float*)d_in[4];
    const float* ba = (const float*)d_in[5];
    const float* Wb = (const float*)d_in[6];
    const float* bb = (const float*)d_in[7];
    const float* Wg = (const float*)d_in[8];
    const float* bg = (const float*)d_in[9];
    const float* WaR = (const float*)d_in[10];
    const float* baR = (const float*)d_in[11];
    const float* Wo = (const float*)d_in[12];
    const float* lnw = (const float*)d_in[13];
    const float* lnb = (const float*)d_in[14];

    const size_t SZH = 16777216ULL;   // fp16/bf16 plane bytes (8192*1024*2)
    const size_t SZF = 33554432ULL;   // fp32 plane bytes (8192*1024*4)
    const size_t need32 = 5 * SZF + SZH + 2097152ULL;   // ~178 MB
    const size_t need16 = 6 * SZH + 2097152ULL;         // ~98 MB

    char* ws = (char*)d_ws;
    // d_out doubles as scratch for bf16 projection weights (10 MB of 32 MB);
    // only read by k_proj, fully overwritten by k_out at the end.
    unsigned short* wbf = (unsigned short*)d_out;
    WPtrs wp{Wq, Wk, Wv, Wa, WaR};

    if (ws_size >= need32) {
        // ---------------- fp32 stream path ----------------
        float* qb = (float*)(ws + 0 * SZF);
        float* kb = (float*)(ws + 1 * SZF);
        float* vb = (float*)(ws + 2 * SZF);
        float* ab = (float*)(ws + 3 * SZF);
        float* aRb = (float*)(ws + 4 * SZF);
        unsigned short* xn = (unsigned short*)(ws + 5 * SZF);   // bf16; reused for o
        f32x2* bgpk = (f32x2*)(ws + 5 * SZF + SZH);
        unsigned short* wobf = (unsigned short*)qb;             // qb dead after scan

        k_wconv<<<dim3(512, 5), dim3(256), 0, stream>>>(wp, wbf);
        k_ln<<<dim3(MTOT), dim3(256), 0, stream>>>(x, lnw, lnb, xn);
        k_proj<float><<<dim3(64, 40), dim3(256), 0, stream>>>(xn, wbf, ba, baR, qb, kb, vb, ab, aRb);
        k_bg<<<dim3(MTOT), dim3(256), 0, stream>>>(xn, Wb, bb, Wg, bg, bgpk);
        k_prep32<<<dim3(MTOT * NH / 16), dim3(256), 0, stream>>>(kb);
        k_scan32<<<dim3(256), dim3(256), 0, stream>>>(qb, kb, vb, ab, aRb, bgpk, xn);
        k_cvt1<<<dim3(512), dim3(256), 0, stream>>>(Wo, wobf);
        k_out<<<dim3(64, 8), dim3(256), 0, stream>>>(xn, wobf, x, (float*)d_out);
    } else if (ws_size >= need16) {
        // ---------------- fp16 fallback (previous proven path) ----------------
        __half* qb = (__half*)(ws + 0 * SZH);
        __half* kb = (__half*)(ws + 1 * SZH);
        __half* vb = (__half*)(ws + 2 * SZH);
        __half* ab = (__half*)(ws + 3 * SZH);
        __half* aRb = (__half*)(ws + 4 * SZH);
        unsigned short* xn = (unsigned short*)(ws + 5 * SZH);
        f32x2* bgpk = (f32x2*)(ws + 6 * SZH);
        unsigned short* wobf = (unsigned short*)qb;

        k_wconv<<<dim3(512, 5), dim3(256), 0, stream>>>(wp, wbf);
        k_ln<<<dim3(MTOT), dim3(256), 0, stream>>>(x, lnw, lnb, xn);
        k_proj<_Float16><<<dim3(64, 40), dim3(256), 0, stream>>>(
            xn, wbf, ba, baR, (_Float16*)qb, (_Float16*)kb, (_Float16*)vb, (_Float16*)ab, (_Float16*)aRb);
        k_bg<<<dim3(MTOT), dim3(256), 0, stream>>>(xn, Wb, bb, Wg, bg, bgpk);
        k_prep16<<<dim3(MTOT * NH / 16), dim3(256), 0, stream>>>(kb);
        k_scan16<<<dim3(256), dim3(256), 0, stream>>>(qb, kb, vb, ab, aRb, bgpk, xn);
        k_cvt1<<<dim3(512), dim3(256), 0, stream>>>(Wo, wobf);
        k_out<<<dim3(64, 8), dim3(256), 0, stream>>>(xn, wobf, x, (float*)d_out);
    }
}

// Round 7
// 795.312 us; speedup vs baseline: 1.4853x; 1.0387x over previous
//
#include <hip/hip_runtime.h>
#include <hip/hip_fp16.h>

#define B_SZ 4
#define T_SEQ 2048
#define NH 16
#define HD 64
#define DMODEL 1024
#define MTOT (B_SZ * T_SEQ)   // 8192

typedef __bf16 bf16x8 __attribute__((ext_vector_type(8)));
typedef float f32x4 __attribute__((ext_vector_type(4)));
typedef float f32x2 __attribute__((ext_vector_type(2)));
typedef _Float16 f16x4 __attribute__((ext_vector_type(4)));

__device__ __forceinline__ unsigned short f2bf(float f) {
    union { float f; unsigned int i; } c; c.f = f;
    unsigned int u = c.i;
    u += 0x7fffu + ((u >> 16) & 1u);   // round-to-nearest-even
    return (unsigned short)(u >> 16);
}
__device__ __forceinline__ float sigm(float x) { return 1.f / (1.f + __expf(-x)); }

// async global->LDS DMA, 16B/lane (GEMM staging only)
__device__ __forceinline__ void dma16(const void* g, void* l) {
    __builtin_amdgcn_global_load_lds(
        (const __attribute__((address_space(1))) void*)g,
        (__attribute__((address_space(3))) void*)l, 16, 0, 0);
}

// DPP row_ror butterfly via builtin (compiler inserts hazard nops).
template <int CTRL>
__device__ __forceinline__ float dppadd(float x) {
    int v = __builtin_amdgcn_update_dpp(0, __builtin_bit_cast(int, x), CTRL, 0xf, 0xf, false);
    return x + __builtin_bit_cast(float, v);
}
__device__ __forceinline__ float rowsum16(float x) {
    x = dppadd<0x128>(x);
    x = dppadd<0x124>(x);
    x = dppadd<0x122>(x);
    x = dppadd<0x121>(x);
    return x;
}

// Three interleaved 16-lane row reductions, fused v_add_f32_dpp (1 instr per
// stage). The 3-way interleave puts >=2 instructions between dependent stages
// of each chain (VALU->DPP hazard); leading s_nop 1 covers the producers.
__device__ __forceinline__ void rowsum3(float& a, float& b, float& c) {
    asm volatile(
        "s_nop 1\n\t"
        "v_add_f32_dpp %0, %0, %0 row_ror:8 row_mask:0xf bank_mask:0xf\n\t"
        "v_add_f32_dpp %1, %1, %1 row_ror:8 row_mask:0xf bank_mask:0xf\n\t"
        "v_add_f32_dpp %2, %2, %2 row_ror:8 row_mask:0xf bank_mask:0xf\n\t"
        "v_add_f32_dpp %0, %0, %0 row_ror:4 row_mask:0xf bank_mask:0xf\n\t"
        "v_add_f32_dpp %1, %1, %1 row_ror:4 row_mask:0xf bank_mask:0xf\n\t"
        "v_add_f32_dpp %2, %2, %2 row_ror:4 row_mask:0xf bank_mask:0xf\n\t"
        "v_add_f32_dpp %0, %0, %0 row_ror:2 row_mask:0xf bank_mask:0xf\n\t"
        "v_add_f32_dpp %1, %1, %1 row_ror:2 row_mask:0xf bank_mask:0xf\n\t"
        "v_add_f32_dpp %2, %2, %2 row_ror:2 row_mask:0xf bank_mask:0xf\n\t"
        "v_add_f32_dpp %0, %0, %0 row_ror:1 row_mask:0xf bank_mask:0xf\n\t"
        "v_add_f32_dpp %1, %1, %1 row_ror:1 row_mask:0xf bank_mask:0xf\n\t"
        "v_add_f32_dpp %2, %2, %2 row_ror:1 row_mask:0xf bank_mask:0xf"
        : "+v"(a), "+v"(b), "+v"(c));
}

// ---------------------------------------------------------------- LayerNorm
__global__ __launch_bounds__(256, 1) void k_ln(const float* __restrict__ x,
                                               const float* __restrict__ lnw,
                                               const float* __restrict__ lnb,
                                               unsigned short* __restrict__ xn) {
    const int m = blockIdx.x;
    const int t = threadIdx.x;
    float4 xv = ((const float4*)(x + (size_t)m * DMODEL))[t];
    float s = xv.x + xv.y + xv.z + xv.w;
    float s2 = xv.x * xv.x + xv.y * xv.y + xv.z * xv.z + xv.w * xv.w;
#pragma unroll
    for (int off = 32; off >= 1; off >>= 1) {
        s += __shfl_xor(s, off);
        s2 += __shfl_xor(s2, off);
    }
    __shared__ float red[8];
    const int wid = t >> 6;
    if ((t & 63) == 0) { red[wid] = s; red[4 + wid] = s2; }
    __syncthreads();
    if (t == 0) {
        float su = red[0] + red[1] + red[2] + red[3];
        float sq = red[4] + red[5] + red[6] + red[7];
        float mu = su * (1.f / DMODEL);
        float var = sq * (1.f / DMODEL) - mu * mu;
        red[0] = mu;
        red[1] = rsqrtf(var + 1e-5f);
    }
    __syncthreads();
    float mu = red[0], rstd = red[1];
    float4 w4 = ((const float4*)lnw)[t];
    float4 b4 = ((const float4*)lnb)[t];
    ushort4 o;
    o.x = f2bf((xv.x - mu) * rstd * w4.x + b4.x);
    o.y = f2bf((xv.y - mu) * rstd * w4.y + b4.y);
    o.z = f2bf((xv.z - mu) * rstd * w4.z + b4.z);
    o.w = f2bf((xv.w - mu) * rstd * w4.w + b4.w);
    ((ushort4*)(xn + (size_t)m * DMODEL))[t] = o;
}

// ------------------------------------------- fp32 -> bf16 weight conversion
struct WPtrs { const float* p0; const float* p1; const float* p2; const float* p3; const float* p4; };

__global__ __launch_bounds__(256, 1) void k_wconv(WPtrs w, unsigned short* __restrict__ dst) {
    const int plane = blockIdx.y;
    const float* src = plane == 0 ? w.p0 : plane == 1 ? w.p1 : plane == 2 ? w.p2
                                                             : plane == 3 ? w.p3 : w.p4;
    const size_t i = ((size_t)blockIdx.x * 256 + threadIdx.x) * 8;
    float4 f0 = *(const float4*)(src + i);
    float4 f1 = *(const float4*)(src + i + 4);
    uint4 o;
    o.x = (unsigned)f2bf(f0.x) | ((unsigned)f2bf(f0.y) << 16);
    o.y = (unsigned)f2bf(f0.z) | ((unsigned)f2bf(f0.w) << 16);
    o.z = (unsigned)f2bf(f1.x) | ((unsigned)f2bf(f1.y) << 16);
    o.w = (unsigned)f2bf(f1.z) | ((unsigned)f2bf(f1.w) << 16);
    *(uint4*)(dst + (size_t)plane * 1048576 + i) = o;
}

__global__ __launch_bounds__(256, 1) void k_cvt1(const float* __restrict__ src,
                                                 unsigned short* __restrict__ dst) {
    const size_t i = ((size_t)blockIdx.x * 256 + threadIdx.x) * 8;
    float4 f0 = *(const float4*)(src + i);
    float4 f1 = *(const float4*)(src + i + 4);
    uint4 o;
    o.x = (unsigned)f2bf(f0.x) | ((unsigned)f2bf(f0.y) << 16);
    o.y = (unsigned)f2bf(f0.z) | ((unsigned)f2bf(f0.w) << 16);
    o.z = (unsigned)f2bf(f1.x) | ((unsigned)f2bf(f1.y) << 16);
    o.w = (unsigned)f2bf(f1.z) | ((unsigned)f2bf(f1.w) << 16);
    *(uint4*)(dst + i) = o;
}

// ------------------------------------------------- 128x128 bf16 MFMA tile GEMM
// 2-deep COUNTED-vmcnt pipeline (T4): tiles kb and kb+1 staged ahead; per
// K-step wait vmcnt(4) (tile kb's 4 loads done, kb+1's 4 remain in flight) --
// NEVER drain to 0 in the loop (round-6 lesson: drain-0 = no pipeline, per
// learn_hip m196/m218). Loads get a full iteration (~300-400cy) to land.
// Safety: (1) wait+barrier before ds_read => all waves' tile-kb data landed;
// (2) lgkmcnt(0)+barrier before staging kb+2 into the just-read buffer =>
// no overwrite while any wave still reads it. Final iteration waits vmcnt(0).
template <int KDIM>
__device__ __forceinline__ void gemm128(const unsigned short* __restrict__ A,
                                        const unsigned short* __restrict__ Bw,
                                        int m0, int n0, f32x4 acc[4][4]) {
    __shared__ __align__(16) unsigned short sA[2 * 128 * 32];
    __shared__ __align__(16) unsigned short sB[2 * 128 * 32];

    const int t = threadIdx.x;
    const int lane = t & 63;
    const int wv = t >> 6;
    const int wm = wv >> 1, wn = wv & 1;
    const int ml = lane & 15, kq = lane >> 4;

#pragma unroll
    for (int i = 0; i < 4; i++)
#pragma unroll
        for (int j = 0; j < 4; j++) {
            f32x4 z; z[0] = 0.f; z[1] = 0.f; z[2] = 0.f; z[3] = 0.f;
            acc[i][j] = z;
        }

    const unsigned short* pA = A + (size_t)m0 * KDIM;
    const unsigned short* pB = Bw + (size_t)n0 * KDIM;
    const unsigned short* gA0 = pA + (size_t)(t >> 2) * KDIM + (t & 3) * 8;
    const unsigned short* gA1 = gA0 + (size_t)64 * KDIM;
    const unsigned short* gB0 = pB + (size_t)(t >> 2) * KDIM + (t & 3) * 8;
    const unsigned short* gB1 = gB0 + (size_t)64 * KDIM;
    unsigned short* lA0 = sA + wv * 512;
    unsigned short* lA1 = lA0 + 2048;
    unsigned short* lB0 = sB + wv * 512;
    unsigned short* lB1 = lB0 + 2048;

    constexpr int NK = KDIM / 32;

    // prologue: stage tile 0 -> buf0, tile 1 -> buf1 (8 loads in flight)
    dma16(gA0, lA0);
    dma16(gA1, lA1);
    dma16(gB0, lB0);
    dma16(gB1, lB1);
    dma16(gA0 + 32, lA0 + 4096);
    dma16(gA1 + 32, lA1 + 4096);
    dma16(gB0 + 32, lB0 + 4096);
    dma16(gB1 + 32, lB1 + 4096);

    for (int kb = 0; kb < NK; kb++) {
        // tile kb complete when only tile kb+1's 4 loads remain outstanding
        if (kb < NK - 1)
            asm volatile("s_waitcnt vmcnt(4)" ::: "memory");
        else
            asm volatile("s_waitcnt vmcnt(0)" ::: "memory");
        __builtin_amdgcn_s_barrier();   // everyone's tile-kb data landed

        const int bo = (kb & 1) * 4096;
        const unsigned short* bA = sA + bo;
        const unsigned short* bB = sB + bo;
        bf16x8 af[4], bfr[4];
#pragma unroll
        for (int mt = 0; mt < 4; mt++)
            af[mt] = *(const bf16x8*)&bA[(wm * 64 + mt * 16 + ml) * 32 + kq * 8];
#pragma unroll
        for (int nt = 0; nt < 4; nt++)
            bfr[nt] = *(const bf16x8*)&bB[(wn * 64 + nt * 16 + ml) * 32 + kq * 8];
        asm volatile("s_waitcnt lgkmcnt(0)" ::: "memory");  // frags in registers
        __builtin_amdgcn_s_barrier();   // all waves done reading buf[kb&1]

        // refill the just-read buffer with tile kb+2 (lands ~1 iter from now)
        if (kb + 2 < NK) {
            const int ko = (kb + 2) * 32;
            dma16(gA0 + ko, lA0 + bo);
            dma16(gA1 + ko, lA1 + bo);
            dma16(gB0 + ko, lB0 + bo);
            dma16(gB1 + ko, lB1 + bo);
        }
#pragma unroll
        for (int mt = 0; mt < 4; mt++)
#pragma unroll
            for (int nt = 0; nt < 4; nt++)
                acc[mt][nt] = __builtin_amdgcn_mfma_f32_16x16x32_bf16(af[mt], bfr[nt], acc[mt][nt], 0, 0, 0);
    }
}

// -------------------------------------------- fused 5-way projection GEMM
// OT = float (fp32 stream path) or _Float16 (fallback)
template <typename OT>
__global__ __launch_bounds__(256, 2) void k_proj(const unsigned short* __restrict__ xn,
                                                 const unsigned short* __restrict__ wbf,
                                                 const float* __restrict__ ba,
                                                 const float* __restrict__ baR,
                                                 OT* __restrict__ qo, OT* __restrict__ ko,
                                                 OT* __restrict__ vo, OT* __restrict__ ao,
                                                 OT* __restrict__ aRo) {
    const int m0 = blockIdx.x * 128;
    const int yt = blockIdx.y;
    const int widx = yt >> 3;
    const int n0 = (yt & 7) * 128;
    const unsigned short* W = wbf + (size_t)widx * 1048576;
    f32x4 acc[4][4];
    gemm128<1024>(xn, W, m0, n0, acc);

    OT* outp = widx == 0 ? qo : widx == 1 ? ko : widx == 2 ? vo : widx == 3 ? ao : aRo;
    const float* bias = (widx == 3) ? ba : (widx == 4) ? baR : (const float*)0;
    const int lane = threadIdx.x & 63;
    const int wv = threadIdx.x >> 6;
    const int wm = wv >> 1, wn = wv & 1;
    const int ml = lane & 15, kq = lane >> 4;
#pragma unroll
    for (int mt = 0; mt < 4; mt++)
#pragma unroll
        for (int nt = 0; nt < 4; nt++) {
            const int rowg = m0 + wm * 64 + mt * 16 + kq * 4;
            const int colg = n0 + wn * 64 + nt * 16 + ml;
            float bval = bias ? bias[colg] : 0.f;
#pragma unroll
            for (int r = 0; r < 4; r++) {
                float v = acc[mt][nt][r];
                if (widx >= 3) v = sigm(v + bval);
                outp[(size_t)(rowg + r) * DMODEL + colg] = (OT)v;
            }
        }
}

// --------------------------------------------------- beta/gamma skinny GEMM
__global__ __launch_bounds__(256, 1) void k_bg(const unsigned short* __restrict__ xn,
                                               const float* __restrict__ Wb,
                                               const float* __restrict__ bb,
                                               const float* __restrict__ Wg,
                                               const float* __restrict__ bgp,
                                               f32x2* __restrict__ bgpk) {
    const int m = blockIdx.x;
    const int t = threadIdx.x;
    const int h = t >> 4, seg = t & 15;
    const ushort4* xr = (const ushort4*)(xn + (size_t)m * DMODEL + seg * 64);
    const float4* wbr = (const float4*)(Wb + (size_t)h * DMODEL + seg * 64);
    const float4* wgr = (const float4*)(Wg + (size_t)h * DMODEL + seg * 64);
    float db = 0.f, dg = 0.f;
#pragma unroll
    for (int u = 0; u < 16; u++) {
        ushort4 a = xr[u];
        float4 w1 = wbr[u], w2 = wgr[u];
        union { unsigned int i; float f; } c0, c1, c2, c3;
        c0.i = ((unsigned int)a.x) << 16; c1.i = ((unsigned int)a.y) << 16;
        c2.i = ((unsigned int)a.z) << 16; c3.i = ((unsigned int)a.w) << 16;
        db += c0.f * w1.x + c1.f * w1.y + c2.f * w1.z + c3.f * w1.w;
        dg += c0.f * w2.x + c1.f * w2.y + c2.f * w2.z + c3.f * w2.w;
    }
#pragma unroll
    for (int off = 1; off < 16; off <<= 1) {
        db += __shfl_xor(db, off);
        dg += __shfl_xor(dg, off);
    }
    if (seg == 0) {
        f32x2 o;
        o[0] = sigm(db + bb[h]);
        o[1] = sigm(dg + bgp[h]);
        bgpk[(size_t)m * NH + h] = o;
    }
}

// ------------------------------------------- k normalization (in-place)
__global__ __launch_bounds__(256, 1) void k_prep16(__half* __restrict__ kb) {
    const int row = blockIdx.x * 16 + (threadIdx.x >> 4);
    const int tr = threadIdx.x & 15;
    const int bh = row >> 11, t = row & 2047;
    const size_t idx = ((size_t)((bh >> 4) * T_SEQ + t)) * DMODEL + (bh & 15) * 64 + tr * 4;
    f16x4 k4 = *(const f16x4*)((const __half*)kb + idx);
    float k0 = (float)k4[0], k1 = (float)k4[1], k2 = (float)k4[2], k3 = (float)k4[3];
    float ss = k0 * k0 + k1 * k1 + k2 * k2 + k3 * k3;
    ss = rowsum16(ss);
    float inv = 1.f / fmaxf(sqrtf(ss), 1e-12f);
    f16x4 o;
    o[0] = (_Float16)(k0 * inv); o[1] = (_Float16)(k1 * inv);
    o[2] = (_Float16)(k2 * inv); o[3] = (_Float16)(k3 * inv);
    *(f16x4*)(kb + idx) = o;
}

__global__ __launch_bounds__(256, 1) void k_prep32(float* __restrict__ kb) {
    const int row = blockIdx.x * 16 + (threadIdx.x >> 4);
    const int tr = threadIdx.x & 15;
    const int bh = row >> 11, t = row & 2047;
    const size_t idx = ((size_t)((bh >> 4) * T_SEQ + t)) * DMODEL + (bh & 15) * 64 + tr * 4;
    f32x4 k4 = *(const f32x4*)(kb + idx);
    float ss = k4[0] * k4[0] + k4[1] * k4[1] + k4[2] * k4[2] + k4[3] * k4[3];
    ss = rowsum16(ss);
    float inv = 1.f / fmaxf(sqrtf(ss), 1e-12f);
    f32x4 o;
    o[0] = k4[0] * inv; o[1] = k4[1] * inv; o[2] = k4[2] * inv; o[3] = k4[3] * inv;
    *(f32x4*)(kb + idx) = o;
}

// ------------------------------------------------------------- the scan, fp32
// ROUND-3/5 PROVEN LAYOUT (362 us): 256 blocks, 16 lanes/column, f32x4/thread,
// fused-DPP reductions. Latency-bound at 1 wave/SIMD; occupancy-doubling via
// lane-split proven NOT to help (round 4). Untouched this round.
// NOTE: T_SEQ % 6 != 0 -> all o-stores guarded by s < T_SEQ.
__global__ __launch_bounds__(256, 1) void k_scan32(const float* __restrict__ qb,
                                                   const float* __restrict__ knb,
                                                   const float* __restrict__ vb,
                                                   const float* __restrict__ ab,
                                                   const float* __restrict__ aRb,
                                                   const f32x2* __restrict__ bgpk,
                                                   unsigned short* __restrict__ ob) {
    const int blk = blockIdx.x;
    const int bh = blk & 63, cg = blk >> 6;   // XCD co-location swizzle
    const int b = bh >> 4, h = bh & 15;
    const int t = threadIdx.x;
    const int col = t >> 4, tr = t & 15;
    const int ii = cg * 16 + col;
    const int j0 = tr * 4;

    const size_t blkoff = (size_t)b * T_SEQ * DMODEL + h * 64;  // block-uniform
    const float* pq = qb + blkoff;
    const float* pk = knb + blkoff;
    const float* pa = ab + blkoff;
    const float* pr = aRb + blkoff;
    const float* pvb = vb + blkoff;
    const f32x2* pbg = bgpk + (size_t)b * T_SEQ * NH + h;
    unsigned short* obp = ob + blkoff + ii;

    f32x2 S01 = {0.f, 0.f}, S23 = {0.f, 0.f}, R01 = {0.f, 0.f}, R23 = {0.f, 0.f};

    f32x4 rk[6], rq[6], ra[6], rr[6];
    float rv[6];
    f32x2 rbg[6];

#pragma unroll
    for (int p = 0; p < 6; p++) {
        const size_t vo = (size_t)p * DMODEL;
        rk[p] = *(const f32x4*)(pk + vo + j0);
        rq[p] = *(const f32x4*)(pq + vo + j0);
        ra[p] = *(const f32x4*)(pa + vo + j0);
        rr[p] = *(const f32x4*)(pr + vo + j0);
        rv[p] = pvb[vo + ii];
        rbg[p] = pbg[(size_t)p * NH];
    }

    float oA, oB, oC;

#define SCAN_BODY32(P, ODEST)                                                       \
    {                                                                               \
        const f32x2 kn01 = {rk[P][0], rk[P][1]}, kn23 = {rk[P][2], rk[P][3]};       \
        const f32x2 a01 = {ra[P][0], ra[P][1]}, a23 = {ra[P][2], ra[P][3]};         \
        const f32x2 x01 = {rr[P][0], rr[P][1]}, x23 = {rr[P][2], rr[P][3]};         \
        const f32x2 q01 = {rq[P][0], rq[P][1]}, q23 = {rq[P][2], rq[P][3]};         \
        const float vc = rv[P];                                                     \
        const float beta = rbg[P][0], gamma = rbg[P][1];                            \
        const f32x2 Sd01 = a01 * S01, Sd23 = a23 * S23;                             \
        const f32x2 Rd01 = x01 * R01, Rd23 = x23 * R23;                             \
        const f32x2 pv2 = S01 * kn01 + S23 * kn23;                                  \
        const f32x2 kp2 = Sd01 * kn01 + Sd23 * kn23;                                \
        const f32x2 kR2 = Rd01 * kn01 + Rd23 * kn23;                                \
        float pred = pv2[0] + pv2[1];                                               \
        float kp = kp2[0] + kp2[1];                                                 \
        float kpR = kR2[0] + kR2[1];                                                \
        rowsum3(pred, kp, kpR);                                                     \
        const float rres = fminf(fmaxf(vc - pred, -1.f), 1.f);                      \
        const float cS = beta * (vc - kp);                                          \
        const float cR = gamma * (rres - kpR);                                      \
        const f32x2 cS2 = {cS, cS}, cR2 = {cR, cR};                                 \
        S01 = cS2 * kn01 + Sd01; S23 = cS2 * kn23 + Sd23;                           \
        R01 = cR2 * kn01 + Rd01; R23 = cR2 * kn23 + Rd23;                           \
        const f32x2 ov = (S01 + R01) * q01 + (S23 + R23) * q23;                     \
        ODEST = ov[0] + ov[1];                                                      \
        /* prefetch step st+P+6 into slot P (old slot value fully consumed) */      \
        {                                                                           \
            const int sp = (st + (P) + 6) & (T_SEQ - 1);                            \
            const size_t vo = (size_t)sp * DMODEL;                                  \
            rk[P] = *(const f32x4*)(pk + vo + j0);                                  \
            rq[P] = *(const f32x4*)(pq + vo + j0);                                  \
            ra[P] = *(const f32x4*)(pa + vo + j0);                                  \
            rr[P] = *(const f32x4*)(pr + vo + j0);                                  \
            rv[P] = pvb[vo + ii];                                                   \
            rbg[P] = pbg[(size_t)sp * NH];                                          \
        }                                                                           \
    }

#define FLUSH3(SBASE)                                                               \
    {                                                                               \
        rowsum3(oA, oB, oC);                                                        \
        if (tr == 0) {                                                              \
            if ((SBASE) < T_SEQ)     obp[(size_t)(SBASE) * DMODEL] = f2bf(oA);      \
            if ((SBASE) + 1 < T_SEQ) obp[(size_t)((SBASE) + 1) * DMODEL] = f2bf(oB);\
            if ((SBASE) + 2 < T_SEQ) obp[(size_t)((SBASE) + 2) * DMODEL] = f2bf(oC);\
        }                                                                           \
    }

    for (int st = 0; st < T_SEQ; st += 6) {
        SCAN_BODY32(0, oA)
        SCAN_BODY32(1, oB)
        SCAN_BODY32(2, oC)
        FLUSH3(st)
        SCAN_BODY32(3, oA)
        SCAN_BODY32(4, oB)
        SCAN_BODY32(5, oC)
        FLUSH3(st + 3)
    }
#undef SCAN_BODY32
#undef FLUSH3
}

// ------------------------------------------------------------- the scan, fp16
// Fallback path (proven 944us kernel) used if ws_size is too small for fp32
// stream planes.
__global__ __launch_bounds__(256, 1) void k_scan16(const __half* __restrict__ qb,
                                                   const __half* __restrict__ knb,
                                                   const __half* __restrict__ vb,
                                                   const __half* __restrict__ ab,
                                                   const __half* __restrict__ aRb,
                                                   const f32x2* __restrict__ bgpk,
                                                   unsigned short* __restrict__ ob) {
    const int blk = blockIdx.x;
    const int bh = blk & 63, cg = blk >> 6;
    const int b = bh >> 4, h = bh & 15;
    const int t = threadIdx.x;
    const int col = t >> 4, tr = t & 15;
    const int ii = cg * 16 + col;
    const int j0 = tr * 4;

    const size_t vecbase = ((size_t)b * T_SEQ) * DMODEL + h * 64 + j0;
    const size_t vbase = ((size_t)b * T_SEQ) * DMODEL + h * 64 + ii;
    const size_t bgbase = ((size_t)b * T_SEQ) * NH + h;

    const __half* pk = knb + vecbase;
    const __half* pq = qb + vecbase;
    const __half* pa = ab + vecbase;
    const __half* pr = aRb + vecbase;

    float S0 = 0, S1 = 0, S2 = 0, S3 = 0, R0 = 0, R1 = 0, R2 = 0, R3 = 0;

    f16x4 rk[6], rq[6], ra[6], rr[6];
    __half rv[6];
    f32x2 rbg[6];
    f32x4 fkn[6], fq[6], fa[6], fr[6];
    float fv[6];

#pragma unroll
    for (int p = 0; p < 6; p++) {
        const size_t voff = (size_t)p * DMODEL;
        rk[p] = *(const f16x4*)(pk + voff);
        rq[p] = *(const f16x4*)(pq + voff);
        ra[p] = *(const f16x4*)(pa + voff);
        rr[p] = *(const f16x4*)(pr + voff);
        rv[p] = vb[vbase + voff];
        rbg[p] = bgpk[bgbase + (size_t)p * NH];
    }
    fkn[0][0] = (float)rk[0][0]; fkn[0][1] = (float)rk[0][1]; fkn[0][2] = (float)rk[0][2]; fkn[0][3] = (float)rk[0][3];
    fq[0][0] = (float)rq[0][0]; fq[0][1] = (float)rq[0][1]; fq[0][2] = (float)rq[0][2]; fq[0][3] = (float)rq[0][3];
    fa[0][0] = (float)ra[0][0]; fa[0][1] = (float)ra[0][1]; fa[0][2] = (float)ra[0][2]; fa[0][3] = (float)ra[0][3];
    fr[0][0] = (float)rr[0][0]; fr[0][1] = (float)rr[0][1]; fr[0][2] = (float)rr[0][2]; fr[0][3] = (float)rr[0][3];
    fv[0] = (float)rv[0];

#define SCAN_BODY(P, PN)                                                              \
    {                                                                                 \
        const int s = st + (P);                                                       \
        const float beta = rbg[P][0], gamma = rbg[P][1];                              \
        {                                                                             \
            const size_t voff = (size_t)((s + 6) & (T_SEQ - 1)) * DMODEL;             \
            rk[P] = *(const f16x4*)(pk + voff);                                       \
            rq[P] = *(const f16x4*)(pq + voff);                                       \
            ra[P] = *(const f16x4*)(pa + voff);                                       \
            rr[P] = *(const f16x4*)(pr + voff);                                       \
            rv[P] = vb[vbase + voff];                                                 \
        }                                                                             \
        fkn[PN][0] = (float)rk[PN][0]; fkn[PN][1] = (float)rk[PN][1];                 \
        fkn[PN][2] = (float)rk[PN][2]; fkn[PN][3] = (float)rk[PN][3];                 \
        fq[PN][0] = (float)rq[PN][0]; fq[PN][1] = (float)rq[PN][1];                   \
        fq[PN][2] = (float)rq[PN][2]; fq[PN][3] = (float)rq[PN][3];                   \
        fa[PN][0] = (float)ra[PN][0]; fa[PN][1] = (float)ra[PN][1];                   \
        fa[PN][2] = (float)ra[PN][2]; fa[PN][3] = (float)ra[PN][3];                   \
        fr[PN][0] = (float)rr[PN][0]; fr[PN][1] = (float)rr[PN][1];                   \
        fr[PN][2] = (float)rr[PN][2]; fr[PN][3] = (float)rr[PN][3];                   \
        fv[PN] = (float)rv[PN];                                                       \
        {                                                                             \
            const float kn0 = fkn[P][0], kn1 = fkn[P][1], kn2 = fkn[P][2], kn3 = fkn[P][3]; \
            const float a0 = fa[P][0], a1 = fa[P][1], a2 = fa[P][2], a3 = fa[P][3];   \
            const float x0 = fr[P][0], x1 = fr[P][1], x2 = fr[P][2], x3 = fr[P][3];   \
            const float vc = fv[P];                                                   \
            float pred = S0 * kn0 + S1 * kn1 + S2 * kn2 + S3 * kn3;                   \
            float Sd0 = a0 * S0, Sd1 = a1 * S1, Sd2 = a2 * S2, Sd3 = a3 * S3;         \
            float Rd0 = x0 * R0, Rd1 = x1 * R1, Rd2 = x2 * R2, Rd3 = x3 * R3;         \
            float kp = Sd0 * kn0 + Sd1 * kn1 + Sd2 * kn2 + Sd3 * kn3;                 \
            float kpR = Rd0 * kn0 + Rd1 * kn1 + Rd2 * kn2 + Rd3 * kn3;                \
            pred = rowsum16(pred);                                                    \
            kp = rowsum16(kp);                                                        \
            kpR = rowsum16(kpR);                                                      \
            const float rres = fminf(fmaxf(vc - pred, -1.f), 1.f);                    \
            const float cS = beta * (vc - kp);                                        \
            const float cR = gamma * (rres - kpR);                                    \
            S0 = fmaf(cS, kn0, Sd0); S1 = fmaf(cS, kn1, Sd1);                         \
            S2 = fmaf(cS, kn2, Sd2); S3 = fmaf(cS, kn3, Sd3);                         \
            R0 = fmaf(cR, kn0, Rd0); R1 = fmaf(cR, kn1, Rd1);                         \
            R2 = fmaf(cR, kn2, Rd2); R3 = fmaf(cR, kn3, Rd3);                         \
            float o = (S0 + R0) * fq[P][0] + (S1 + R1) * fq[P][1] +                   \
                      (S2 + R2) * fq[P][2] + (S3 + R3) * fq[P][3];                    \
            o = rowsum16(o);                                                          \
            if (tr == 0 && s < T_SEQ)                                                 \
                ob[vbase + (size_t)s * DMODEL] = f2bf(o);                             \
        }                                                                             \
        rbg[P] = bgpk[bgbase + (size_t)((s + 6) & (T_SEQ - 1)) * NH];                 \
    }

    for (int st = 0; st < T_SEQ; st += 6) {
        SCAN_BODY(0, 1)
        SCAN_BODY(1, 2)
        SCAN_BODY(2, 3)
        SCAN_BODY(3, 4)
        SCAN_BODY(4, 5)
        SCAN_BODY(5, 0)
    }
#undef SCAN_BODY
}

// ---------------------------------------------------- output GEMM + residual
__global__ __launch_bounds__(256, 2) void k_out(const unsigned short* __restrict__ ob,
                                                const unsigned short* __restrict__ wobf,
                                                const float* __restrict__ x,
                                                float* __restrict__ out) {
    const int m0 = blockIdx.x * 128;
    const int n0 = blockIdx.y * 128;
    f32x4 acc[4][4];
    gemm128<1024>(ob, wobf, m0, n0, acc);
    const int lane = threadIdx.x & 63;
    const int wv = threadIdx.x >> 6;
    const int wm = wv >> 1, wn = wv & 1;
    const int ml = lane & 15, kq = lane >> 4;
#pragma unroll
    for (int mt = 0; mt < 4; mt++)
#pragma unroll
        for (int nt = 0; nt < 4; nt++) {
            const int rowg = m0 + wm * 64 + mt * 16 + kq * 4;
            const int colg = n0 + wn * 64 + nt * 16 + ml;
#pragma unroll
            for (int r = 0; r < 4; r++) {
                size_t idx = (size_t)(rowg + r) * DMODEL + colg;
                out[idx] = acc[mt][nt][r] + x[idx];
            }
        }
}

extern "C" void kernel_launch(void* const* d_in, const int* in_sizes, int n_in,
                              void* d_out, int out_size, void* d_ws, size_t ws_size,
                              hipStream_t stream) {
    const float* x = (const float*)d_in[0];
    const float* Wq = (const float*)d_in[1];
    const float* Wk = (const float*)d_in[2];
    const float* Wv = (const float*)d_in[3];
    const float* Wa = (const float*)d_in[4];
    const float* ba = (const float*)d_in[5];
    const float* Wb = (const float*)d_in[6];
    const float* bb = (const float*)d_in[7];
    const float* Wg = (const float*)d_in[8];
    const float* bg = (const float*)d_in[9];
    const float* WaR = (const float*)d_in[10];
    const float* baR = (const float*)d_in[11];
    const float* Wo = (const float*)d_in[12];
    const float* lnw = (const float*)d_in[13];
    const float* lnb = (const float*)d_in[14];

    const size_t SZH = 16777216ULL;   // fp16/bf16 plane bytes (8192*1024*2)
    const size_t SZF = 33554432ULL;   // fp32 plane bytes (8192*1024*4)
    const size_t need32 = 5 * SZF + SZH + 2097152ULL;   // ~178 MB
    const size_t need16 = 6 * SZH + 2097152ULL;         // ~98 MB

    char* ws = (char*)d_ws;
    // d_out doubles as scratch for bf16 projection weights (10 MB of 32 MB);
    // only read by k_proj, fully overwritten by k_out at the end.
    unsigned short* wbf = (unsigned short*)d_out;
    WPtrs wp{Wq, Wk, Wv, Wa, WaR};

    if (ws_size >= need32) {
        // ---------------- fp32 stream path ----------------
        float* qb = (float*)(ws + 0 * SZF);
        float* kb = (float*)(ws + 1 * SZF);
        float* vb = (float*)(ws + 2 * SZF);
        float* ab = (float*)(ws + 3 * SZF);
        float* aRb = (float*)(ws + 4 * SZF);
        unsigned short* xn = (unsigned short*)(ws + 5 * SZF);   // bf16; reused for o
        f32x2* bgpk = (f32x2*)(ws + 5 * SZF + SZH);
        unsigned short* wobf = (unsigned short*)qb;             // qb dead after scan

        k_wconv<<<dim3(512, 5), dim3(256), 0, stream>>>(wp, wbf);
        k_ln<<<dim3(MTOT), dim3(256), 0, stream>>>(x, lnw, lnb, xn);
        k_proj<float><<<dim3(64, 40), dim3(256), 0, stream>>>(xn, wbf, ba, baR, qb, kb, vb, ab, aRb);
        k_bg<<<dim3(MTOT), dim3(256), 0, stream>>>(xn, Wb, bb, Wg, bg, bgpk);
        k_prep32<<<dim3(MTOT * NH / 16), dim3(256), 0, stream>>>(kb);
        k_scan32<<<dim3(256), dim3(256), 0, stream>>>(qb, kb, vb, ab, aRb, bgpk, xn);
        k_cvt1<<<dim3(512), dim3(256), 0, stream>>>(Wo, wobf);
        k_out<<<dim3(64, 8), dim3(256), 0, stream>>>(xn, wobf, x, (float*)d_out);
    } else if (ws_size >= need16) {
        // ---------------- fp16 fallback (previous proven path) ----------------
        __half* qb = (__half*)(ws + 0 * SZH);
        __half* kb = (__half*)(ws + 1 * SZH);
        __half* vb = (__half*)(ws + 2 * SZH);
        __half* ab = (__half*)(ws + 3 * SZH);
        __half* aRb = (__half*)(ws + 4 * SZH);
        unsigned short* xn = (unsigned short*)(ws + 5 * SZH);
        f32x2* bgpk = (f32x2*)(ws + 6 * SZH);
        unsigned short* wobf = (unsigned short*)qb;

        k_wconv<<<dim3(512, 5), dim3(256), 0, stream>>>(wp, wbf);
        k_ln<<<dim3(MTOT), dim3(256), 0, stream>>>(x, lnw, lnb, xn);
        k_proj<_Float16><<<dim3(64, 40), dim3(256), 0, stream>>>(
            xn, wbf, ba, baR, (_Float16*)qb, (_Float16*)kb, (_Float16*)vb, (_Float16*)ab, (_Float16*)aRb);
        k_bg<<<dim3(MTOT), dim3(256), 0, stream>>>(xn, Wb, bb, Wg, bg, bgpk);
        k_prep16<<<dim3(MTOT * NH / 16), dim3(256), 0, stream>>>(kb);
        k_scan16<<<dim3(256), dim3(256), 0, stream>>>(qb, kb, vb, ab, aRb, bgpk, xn);
        k_cvt1<<<dim3(512), dim3(256), 0, stream>>>(Wo, wobf);
        k_out<<<dim3(64, 8), dim3(256), 0, stream>>>(xn, wobf, x, (float*)d_out);
    }
}